// Round 13
// baseline (211.571 us; speedup 1.0000x reference)
//
#include <hip/hip_runtime.h>
#include <hip/hip_bf16.h>

#define DEVINL static __device__ __forceinline__

typedef __attribute__((ext_vector_type(4))) float f32x4;
typedef __attribute__((ext_vector_type(8))) short bf16x8;

DEVINL short f2bf(float f) {
  __hip_bfloat16 h = __float2bfloat16(f);
  union { __hip_bfloat16 h; short s; } u; u.h = h; return u.s;
}
DEVINL float bf2f(short s) {
  union { unsigned u; float f; } v; v.u = ((unsigned)(unsigned short)s) << 16;
  return v.f;
}
DEVINL float ldf(float x) { return x; }
DEVINL float ldf(short x) { return bf2f(x); }

// ---------------- f32 -> bf16 convert, 4 elems/thread ----------------
__global__ void k_cvt(const float* __restrict__ in, short* __restrict__ out, int n4) {
  int i = blockIdx.x * blockDim.x + threadIdx.x;
  if (i >= n4) return;
  const float4 v = reinterpret_cast<const float4*>(in)[i];
  short4 o;
  o.x = f2bf(v.x); o.y = f2bf(v.y); o.z = f2bf(v.z); o.w = f2bf(v.w);
  reinterpret_cast<short4*>(out)[i] = o;
}

// ------- batched transpose [batch][R][C] -> [batch][C][R], out bf16 -------
// PERM (C==128 only): out-row p for input col h chosen so the 256^2 GEMM's
// epilogue thread holds RoPE pairs (h, h+64) in adjacent j-frags:
//   h = g + 64*hi, g = 32*u + 16*wcH + lr  ->  p = wcH*64 + (2u+hi)*16 + lr
template <typename Tin, bool PERM>
__global__ void k_tr(const Tin* __restrict__ in, short* __restrict__ out, int R, int C) {
  __shared__ float tile[32][33];
  const int bz = blockIdx.z;
  const int r0 = blockIdx.y * 32, c0 = blockIdx.x * 32;
  const int tx = threadIdx.x & 31, ty = threadIdx.x >> 5;  // ty in 0..7
  const Tin* ip = in + (size_t)bz * R * C;
  short* op = out + (size_t)bz * R * C;
#pragma unroll
  for (int k = 0; k < 4; k++)
    tile[ty + k * 8][tx] = ldf(ip[(size_t)(r0 + ty + k * 8) * C + c0 + tx]);
  __syncthreads();
#pragma unroll
  for (int k = 0; k < 4; k++) {
    const int cc = c0 + ty + k * 8;  // output row (= input col)
    int p = cc;
    if (PERM) {
      const int hi = cc >> 6, g = cc & 63;
      p = ((g >> 4) & 1) * 64 + ((g >> 5) * 2 + hi) * 16 + (g & 15);
    }
    op[(size_t)p * R + r0 + tx] = f2bf(tile[tx][ty + k * 8]);
  }
}

#define GBAR __builtin_amdgcn_s_barrier()
#define LGK asm volatile("s_waitcnt lgkmcnt(0)")
#define PR1 __builtin_amdgcn_s_setprio(1)
#define PR0 __builtin_amdgcn_s_setprio(0)

// stage one half-tile: LN x global_load_lds(16B)/thread; LDS linear, src pre-swizzled
template <int LN>
DEVINL void stage(char* dst, const short* src, int K, int tid) {
#pragma unroll
  for (int L = 0; L < LN; L++) {
    const int loc = L * 8192 + tid * 16;
    const int row = loc >> 7;
    const int gsw = ((loc >> 4) & 7) ^ (row & 7);
    __builtin_amdgcn_global_load_lds(
        (const __attribute__((address_space(1))) void*)(src + (size_t)row * K + gsw * 8),
        (__attribute__((address_space(3))) void*)(dst + loc), 16, 0, 0);
  }
}

// =============== m201-port 256x256x64 8-phase GEMM, fused QKV+RoPE ===============
// 512 thr, 8 waves: wave (wr=w>>2, wc=w&3) owns contiguous rows [wr*128,+128) x
// cols [wc*64,+64). acc[8][4]. Quadrant walk with operand carry; ONE half-tile
// stage per phase (ring: Ph0 A1h1<-o, Ph1 B1h0<-o, Ph2 B1h1<-o, Ph3 A0h0<-e2,
// Ph4 A0h1<-e2, Ph5 B0h0<-e2, Ph6 B0h1<-e2, Ph7 A1h0<-o2); counted vmcnt(2)
// only at Ph3/Ph7 ends (enforces the 4 halves needed next K-tile; 1-4 ph slack).

#define QRDA(BUF, HALF)                                                                \
  { _Pragma("unroll")                                                                  \
    for (int kf_ = 0; kf_ < 4; kf_++) {                                                \
      _Pragma("unroll")                                                                \
      for (int kk_ = 0; kk_ < 2; kk_++) {                                              \
        const int row_ = wr * 128 + ((HALF) * 4 + kf_) * 16 + lr;                      \
        a[kf_ * 2 + kk_] = *(const bf16x8*)((BUF) + row_ * 128 +                       \
                                            (((kk_ * 4 + lu) ^ (lr & 7)) << 4));       \
      } } }

#define QRDB(BUF, HALF)                                                                \
  { _Pragma("unroll")                                                                  \
    for (int jf_ = 0; jf_ < 2; jf_++) {                                                \
      _Pragma("unroll")                                                                \
      for (int kk_ = 0; kk_ < 2; kk_++) {                                              \
        const int row_ = wc * 64 + ((HALF) * 2 + jf_) * 16 + lr;                       \
        b[jf_ * 2 + kk_] = *(const bf16x8*)((BUF) + row_ * 128 +                       \
                                            (((kk_ * 4 + lu) ^ (lr & 7)) << 4));       \
      } } }

#define QMF(FO, JO)                                                                    \
  { _Pragma("unroll")                                                                  \
    for (int kf_ = 0; kf_ < 4; kf_++)                                                  \
      { _Pragma("unroll")                                                              \
        for (int jf_ = 0; jf_ < 2; jf_++)                                              \
          { _Pragma("unroll")                                                          \
            for (int kk_ = 0; kk_ < 2; kk_++)                                          \
              acc[(FO) * 4 + kf_][(JO) * 2 + jf_] =                                    \
                  __builtin_amdgcn_mfma_f32_16x16x32_bf16(                             \
                      a[kf_ * 2 + kk_], b[jf_ * 2 + kk_],                              \
                      acc[(FO) * 4 + kf_][(JO) * 2 + jf_], 0, 0, 0);                   \
          } } }

#define SAH(BUF, H, T) stage<2>((BUF) + (H) * 16384, Am + (size_t)((H) * 128) * K + (T) * 64, K, tid)
#define SBH(BUF, H, T) stage<2>((BUF) + (H) * 16384, Bn + (size_t)((H) * 128) * K + (T) * 64, K, tid)
#define VM2 asm volatile("s_waitcnt vmcnt(2)")

__global__ __launch_bounds__(512, 2) void k_gqkv(
    const short* __restrict__ A, const short* __restrict__ Bt,
    void* __restrict__ Out0, void* __restrict__ Out1, int K) {
  extern __shared__ __align__(16) char sm[];
  char* A0 = sm;
  char* A1 = sm + 32768;
  char* B0 = sm + 65536;
  char* B1 = sm + 98304;
  const int m0 = blockIdx.x * 256, n0 = blockIdx.y * 256;
  const int tid = threadIdx.x, lane = tid & 63, w = tid >> 6;
  const int wr = w >> 2, wc = w & 3;
  const int lr = lane & 15, lu = lane >> 4;
  const short* Am = A + (size_t)m0 * K;
  const short* Bn = Bt + (size_t)n0 * K;
  f32x4 acc[8][4] = {};
  bf16x8 a[8], b[4];
  const int NIT = K >> 7, TMAX = (K >> 6) - 1;

  // prologue: t0 all four halves + t1 A-half0; enforce t0 (leave A1h0 in flight)
  SAH(A0, 0, 0); SAH(A0, 1, 0); SBH(B0, 0, 0); SBH(B0, 1, 0);
  SAH(A1, 0, 1);
  VM2; GBAR;

  for (int it = 0; it < NIT; ++it) {
    const int o = 2 * it + 1;
    const int e2 = (2 * it + 2 < TMAX) ? 2 * it + 2 : TMAX;
    const int o2 = (2 * it + 3 < TMAX) ? 2 * it + 3 : TMAX;
    // Ph0: even tile, quad (aLo, bLo)
    QRDA(A0, 0); QRDB(B0, 0); SAH(A1, 1, o);
    GBAR; LGK; PR1; QMF(0, 0); PR0; GBAR;
    // Ph1: (aLo, bHi) — carry a
    QRDB(B0, 1); SBH(B1, 0, o);
    GBAR; LGK; PR1; QMF(0, 1); PR0; GBAR;
    // Ph2: (aHi, bHi) — carry b
    QRDA(A0, 1); SBH(B1, 1, o);
    GBAR; LGK; PR1; QMF(1, 1); PR0; GBAR;
    // Ph3: (aHi, bLo)  [enforce odd-tile halves]
    QRDB(B0, 0); SAH(A0, 0, e2);
    GBAR; LGK; PR1; QMF(1, 0); PR0; VM2; GBAR;
    // Ph4: odd tile, quad (aLo, bLo)
    QRDA(A1, 0); QRDB(B1, 0); SAH(A0, 1, e2);
    GBAR; LGK; PR1; QMF(0, 0); PR0; GBAR;
    // Ph5: (aLo, bHi)
    QRDB(B1, 1); SBH(B0, 0, e2);
    GBAR; LGK; PR1; QMF(0, 1); PR0; GBAR;
    // Ph6: (aHi, bHi)
    QRDA(A1, 1); SBH(B0, 1, e2);
    GBAR; LGK; PR1; QMF(1, 1); PR0; GBAR;
    // Ph7: (aHi, bLo)  [enforce even-tile t2 halves]
    QRDB(B1, 0); SAH(A1, 0, o2);
    GBAR; LGK; PR1; QMF(1, 0); PR0; VM2; GBAR;
  }

  // -------- epilogue: fused RoPE (permuted weights put (h,h+64) in j-pairs) --------
  const bool isq = (n0 < 2048);
  const bool isv = (n0 >= 2560);
  const int wcH = wc & 1;
  const float g0f = (float)(wcH * 16 + lr);
  const float inv0 = __expf(-g0f * (float)(9.210340371976184 / 64.0));
  const float inv1 = __expf(-(g0f + 32.f) * (float)(9.210340371976184 / 64.0));
  const int n_hb = n0 + (wc >> 1) * 128;  // head-block base col
#pragma unroll
  for (int f = 0; f < 8; f++) {
#pragma unroll
    for (int r = 0; r < 4; r++) {
      const int m = m0 + wr * 128 + f * 16 + lu * 4 + r;
      const int bb = m >> 11, t = m & 2047;
#pragma unroll
      for (int u = 0; u < 2; u++) {
        float lo = acc[f][2 * u][r], hi = acc[f][2 * u + 1][r];
        if (!isv) {  // q or k: rotate (and scale q)
          float sn, cs;
          sincosf((float)t * (u ? inv1 : inv0), &sn, &cs);
          const float l2 = lo * cs - hi * sn;
          const float h2 = hi * cs + lo * sn;
          const float scq = isq ? 0.08838834764831845f : 1.0f;
          lo = l2 * scq; hi = h2 * scq;
          const int g = 32 * u + 16 * wcH + lr;
          if (isq) {
            short* q0 = (short*)Out0 + (((size_t)(bb * 16 + (n_hb >> 7))) << 18) +
                        (size_t)t * 128;
            q0[g] = f2bf(lo); q0[g + 64] = f2bf(hi);
          } else {
            const int nnb = n_hb - 2048;
            short* k0 = (short*)Out1 +
                        (((size_t)(((nnb >> 9) * 2 + bb) * 4 + ((nnb >> 7) & 3))) << 18) +
                        (size_t)t * 128;
            k0[g] = f2bf(lo); k0[g + 64] = f2bf(hi);
          }
        } else {  // v passthrough (unpermuted cols)
#pragma unroll
          for (int p2 = 0; p2 < 2; p2++) {
            const int n = n0 + wc * 64 + (2 * u + p2) * 16 + lr;
            const int nn = n - 2048;
            ((short*)Out1)[(((size_t)(((nn >> 9) * 2 + bb) * 4 + ((nn >> 7) & 3))) << 18) +
                           (size_t)t * 128 + (nn & 127)] = f2bf(p2 ? hi : lo);
          }
        }
      }
    }
  }
}

// =================== BMxBNxK 4-phase MFMA GEMM (O-proj, mode 2) ===================
#define VMW { if constexpr (LPA + LPB == 4) asm volatile("s_waitcnt vmcnt(4)"); \
              else asm volatile("s_waitcnt vmcnt(3)"); }

#define SA(BUF, HALF, KT) \
  stage<LPA>((BUF) + (HALF) * (ABY / 2), Am + (size_t)((HALF) * (BM / 2)) * K + (KT) * 64, K, tid)
#define SB(BUF, HALF, KT) \
  stage<LPB>((BUF) + (HALF) * (BBY / 2), Bn + (size_t)((HALF) * (BN / 2)) * K + (KT) * 64, K, tid)

#define RDA(BUF, IH)                                                                   \
  { _Pragma("unroll")                                                                  \
    for (int kf_ = 0; kf_ < KFN; kf_++) {                                              \
      _Pragma("unroll")                                                                \
      for (int kk_ = 0; kk_ < 2; kk_++) {                                              \
        const int row_ = ((IH) * KFN + kf_) * 32 + wr * 16 + lr;                       \
        a[kf_ * 2 + kk_] = *(const bf16x8*)((BUF) + row_ * 128 +                       \
                                            (((kk_ * 4 + lu) ^ (lr & 7)) << 4));       \
      } } }

#define RDB(BUF, JH, ARR)                                                              \
  { _Pragma("unroll")                                                                  \
    for (int jf_ = 0; jf_ < JFN; jf_++) {                                              \
      _Pragma("unroll")                                                                \
      for (int kk_ = 0; kk_ < 2; kk_++) {                                              \
        const int row_ = ((JH) * JFN + jf_) * 64 + wc * 16 + lr;                       \
        ARR[jf_ * 2 + kk_] = *(const bf16x8*)((BUF) + row_ * 128 +                     \
                                              (((kk_ * 4 + lu) ^ (lr & 7)) << 4));     \
      } } }

#define MF(IH, JH, ARR)                                                                \
  { _Pragma("unroll")                                                                  \
    for (int kf_ = 0; kf_ < KFN; kf_++)                                                \
      { _Pragma("unroll")                                                              \
        for (int jf_ = 0; jf_ < JFN; jf_++)                                            \
          { _Pragma("unroll")                                                          \
            for (int kk_ = 0; kk_ < 2; kk_++)                                          \
              acc[(IH) * KFN + kf_][(JH) * JFN + jf_] =                                \
                  __builtin_amdgcn_mfma_f32_16x16x32_bf16(                             \
                      a[kf_ * 2 + kk_], ARR[jf_ * 2 + kk_],                            \
                      acc[(IH) * KFN + kf_][(JH) * JFN + jf_], 0, 0, 0);               \
          } } }

template <int BM, int BN>
__global__ __launch_bounds__(512, 2) void k_gemm256(
    const short* __restrict__ A, const short* __restrict__ Bt,
    void* __restrict__ Out0, int N, int K) {
  constexpr int LPA = BM / 128;
  constexpr int LPB = BN / 128;
  constexpr int KFN = BM / 64;
  constexpr int JFN = BN / 128;
  constexpr int ABY = BM * 128;
  constexpr int BBY = BN * 128;
  extern __shared__ __align__(16) char sm[];
  char* A0 = sm;
  char* A1 = sm + ABY;
  char* B0 = sm + 2 * ABY;
  char* B1 = sm + 2 * ABY + BBY;
  const int lin = blockIdx.x + gridDim.x * blockIdx.y;
  const int m0 = (lin >> 3) * BM, n0 = (lin & 7) * BN;
  const int tid = threadIdx.x, lane = tid & 63, w = tid >> 6;
  const int wr = w & 1, wc = w >> 1;
  const int lr = lane & 15, lu = lane >> 4;
  const short* Am = A + (size_t)m0 * K;
  const short* Bn = Bt + (size_t)n0 * K;
  f32x4 acc[KFN * 2][JFN * 2] = {};
  bf16x8 a[KFN * 2], bJ0[JFN * 2], bJ1[JFN * 2];
  const int NIT = K >> 7;
  const int TMAX = (K >> 6) - 1;

  SA(A0, 0, 0); SB(B0, 1, 0); SA(A0, 1, 0); SB(B0, 0, 0);
  SA(A1, 0, 1); SB(B1, 1, 1);
  VMW; GBAR;

  for (int it = 0; it < NIT; ++it) {
    const int t1 = 2 * it + 1;
    const int t2 = (2 * it + 2 < TMAX) ? 2 * it + 2 : TMAX;
    const int t3 = (2 * it + 3 < TMAX) ? 2 * it + 3 : TMAX;
    RDA(A0, 0); RDB(B0, 0, bJ0); RDB(B0, 1, bJ1); SA(A1, 1, t1); SB(B1, 0, t1);
    GBAR; LGK; PR1; MF(0, 0, bJ0); MF(0, 1, bJ1); PR0; GBAR;
    RDA(A0, 1); SA(A0, 0, t2); SB(B0, 1, t2);
    GBAR; LGK; PR1; MF(1, 1, bJ1); MF(1, 0, bJ0); PR0; VMW; GBAR;
    RDA(A1, 0); RDB(B1, 0, bJ0); RDB(B1, 1, bJ1); SA(A0, 1, t2); SB(B0, 0, t2);
    GBAR; LGK; PR1; MF(0, 0, bJ0); MF(0, 1, bJ1); PR0; GBAR;
    RDA(A1, 1); SA(A1, 0, t3); SB(B1, 1, t3);
    GBAR; LGK; PR1; MF(1, 1, bJ1); MF(1, 0, bJ0); PR0; VMW; GBAR;
  }

#pragma unroll
  for (int k = 0; k < KFN * 2; k++)
#pragma unroll
    for (int j = 0; j < JFN * 2; j++)
#pragma unroll
      for (int r = 0; r < 4; r++) {
        const int m = m0 + k * 32 + wr * 16 + lu * 4 + r;
        const int n = n0 + j * 64 + wc * 16 + lr;
        ((float*)Out0)[(size_t)m * N + n] = acc[k][j][r];
      }
}

// ---------------- flash attention, sliding window + tanh soft-cap ----------------
__global__ __launch_bounds__(256) void k_attn(
    const short* __restrict__ q, const short* __restrict__ kk,
    const short* __restrict__ vT, short* __restrict__ enc) {
  __shared__ __align__(16) short lK[64 * 128];
  __shared__ __align__(16) short lV[128 * 64];
  __shared__ __align__(16) short lP[4][16 * 64];
  const int bn = blockIdx.x, b = bn >> 4, n = bn & 15, kv = n >> 2;
  const int qt0 = (31 - blockIdx.y) * 64;
  const int tid = threadIdx.x, lane = tid & 63, w = tid >> 6;
  const int lr = lane & 15, lu = lane >> 4;
  const short* qbase = q + (((size_t)(b * 16 + n)) << 18) + (size_t)(qt0 + w * 16) * 128;
  bf16x8 qa[4];
#pragma unroll
  for (int c = 0; c < 4; c++)
    qa[c] = *reinterpret_cast<const bf16x8*>(qbase + lr * 128 + c * 32 + lu * 8);
  f32x4 o[8] = {};
  float lsum = 0.f;
  const short* kbase = kk + (((size_t)(b * 4 + kv)) << 18);
  const short* vbase = vT + (((size_t)(b * 4 + kv)) << 18);
  char* lPw = (char*)lP[w];
  const int tw = qt0 + w * 16;
  const int t_row = tw + lu * 4;
  int st0 = qt0 - 1023; if (st0 < 0) st0 = 0;
  st0 >>= 6;
  const int stE = (qt0 + 63) >> 6;
  for (int st = st0; st <= stE; st++) {
    const int s0 = st << 6;
#pragma unroll
    for (int c = 0; c < 4; c++) {
      const int L = w * 4096 + c * 1024 + lane * 16;
      {
        const int s = L >> 8, slot = (L >> 4) & 15;
        const int sp = slot ^ (s & 7);
        __builtin_amdgcn_global_load_lds(
            (const __attribute__((address_space(1))) void*)(kbase + (size_t)(s0 + s) * 128 + sp * 8),
            (__attribute__((address_space(3))) void*)((char*)lK + L), 16, 0, 0);
      }
      {
        const int h = L >> 7, slot = (L >> 4) & 7;
        const int u = slot ^ (h & 7);
        __builtin_amdgcn_global_load_lds(
            (const __attribute__((address_space(1))) void*)(vbase + (size_t)h * 2048 + s0 + u * 8),
            (__attribute__((address_space(3))) void*)((char*)lV + L), 16, 0, 0);
      }
    }
    __syncthreads();
    f32x4 sc[4];
    __builtin_amdgcn_s_setprio(1);
#pragma unroll
    for (int cg = 0; cg < 4; cg++) {
      sc[cg] = (f32x4){0.f, 0.f, 0.f, 0.f};
      const int s = cg * 16 + lr;
      const int sw = (s & 7) << 4;
#pragma unroll
      for (int c = 0; c < 4; c++) {
        bf16x8 kb = *reinterpret_cast<const bf16x8*>((char*)lK + s * 256 + (((c * 4 + lu) << 4) ^ sw));
        sc[cg] = __builtin_amdgcn_mfma_f32_16x16x32_bf16(kb, qa[c], sc[cg], 0, 0, 0);
      }
    }
    __builtin_amdgcn_s_setprio(0);
    const bool allv = (s0 + 63 <= tw) && (s0 + 1008 >= tw);
    if (allv) {
#pragma unroll
      for (int cg = 0; cg < 4; cg++) {
        float pr[4];
#pragma unroll
        for (int r = 0; r < 4; r++) {
          const float x = sc[cg][r];
          const float cap = __builtin_fmaf(x * x * x, -1.3333333e-4f, x);
          const float p = __expf(cap);
          lsum += p;
          pr[r] = p;
        }
        unsigned w0, w1;
        asm("v_cvt_pk_bf16_f32 %0, %1, %2" : "=v"(w0) : "v"(pr[0]), "v"(pr[1]));
        asm("v_cvt_pk_bf16_f32 %0, %1, %2" : "=v"(w1) : "v"(pr[2]), "v"(pr[3]));
        const int sb = (cg * 16 + lu * 4) << 1;
        *(unsigned*)(lPw + (lr << 7) + (sb ^ ((lr & 7) << 4))) = w0;
        *(unsigned*)(lPw + (lr << 7) + ((sb + 4) ^ ((lr & 7) << 4))) = w1;
      }
    } else {
      const int t = tw + lr;
#pragma unroll
      for (int cg = 0; cg < 4; cg++) {
        float pr[4];
#pragma unroll
        for (int r = 0; r < 4; r++) {
          const int s = s0 + cg * 16 + lu * 4 + r;
          const bool valid = (s <= t) & (s + 1024 > t);
          const float x = sc[cg][r];
          const float cap = __builtin_fmaf(x * x * x, -1.3333333e-4f, x);
          float p = __expf(cap);
          p = valid ? p : 0.f;
          lsum += p;
          pr[r] = p;
        }
        unsigned w0, w1;
        asm("v_cvt_pk_bf16_f32 %0, %1, %2" : "=v"(w0) : "v"(pr[0]), "v"(pr[1]));
        asm("v_cvt_pk_bf16_f32 %0, %1, %2" : "=v"(w1) : "v"(pr[2]), "v"(pr[3]));
        const int sb = (cg * 16 + lu * 4) << 1;
        *(unsigned*)(lPw + (lr << 7) + (sb ^ ((lr & 7) << 4))) = w0;
        *(unsigned*)(lPw + (lr << 7) + ((sb + 4) ^ ((lr & 7) << 4))) = w1;
      }
    }
#pragma unroll
    for (int ks = 0; ks < 2; ks++) {
      const bf16x8 pf = *reinterpret_cast<const bf16x8*>(
          lPw + (lr << 7) + ((ks * 64 + lu * 16) ^ ((lr & 7) << 4)));
      __builtin_amdgcn_s_setprio(1);
#pragma unroll
      for (int oc = 0; oc < 8; oc++) {
        const int h = oc * 16 + lr;
        bf16x8 vb = *reinterpret_cast<const bf16x8*>(
            (char*)lV + h * 128 + (((ks * 4 + lu) << 4) ^ ((h & 7) << 4)));
        o[oc] = __builtin_amdgcn_mfma_f32_16x16x32_bf16(pf, vb, o[oc], 0, 0, 0);
      }
      __builtin_amdgcn_s_setprio(0);
    }
    __syncthreads();
  }
  float tot = lsum;
  tot += __shfl_xor(tot, 16, 64);
  tot += __shfl_xor(tot, 32, 64);
  float rs[4];
#pragma unroll
  for (int r = 0; r < 4; r++)
    rs[r] = 1.f / __shfl(tot, lu * 4 + r, 64);
#pragma unroll
  for (int oc = 0; oc < 8; oc++)
#pragma unroll
    for (int r = 0; r < 4; r++) {
      const int t = t_row + r;
      enc[((size_t)b * 2048 + t) * 2048 + n * 128 + oc * 16 + lr] = f2bf(o[oc][r] * rs[r]);
    }
}

extern "C" void kernel_launch(void* const* d_in, const int* in_sizes, int n_in,
                              void* d_out, int out_size, void* d_ws, size_t ws_size,
                              hipStream_t stream) {
  (void)in_sizes; (void)n_in; (void)out_size; (void)ws_size;
  const float* x    = (const float*)d_in[0];
  const float* wq   = (const float*)d_in[3];
  const float* wkv  = (const float*)d_in[4];
  const float* wvec = (const float*)d_in[5];
  char* ws = (char*)d_ws;
  size_t off = 0;
  short* xbf   = (short*)(ws + off); off += (size_t)8388608 * 2;            // x bf16 [B*T][D]
  short* wall  = (short*)(ws + off); off += (size_t)3072 * 2048 * 2;        // [wqT|wkT|wvT] rows x K
  short* wvecT = (short*)(ws + off); off += (size_t)2048 * 2048 * 2;        // [d][nh]
  short* qbuf  = (short*)(ws + off); off += (size_t)2 * 16 * 2048 * 128 * 2; // q bf16 [b][n][t][h]
  short* kvbuf = (short*)(ws + off); off += (size_t)2 * 2 * 4 * 2048 * 128 * 2; // [c][b][kv][t][h]
  short* vTbuf = (short*)(ws + off); off += (size_t)2 * 4 * 128 * 2048 * 2; // v^T [b][kv][h][s]
  short* encb  = (short*)(ws + off); off += (size_t)2 * 2048 * 2048 * 2;    // [b][t][nh]

  hipFuncSetAttribute(reinterpret_cast<const void*>(&k_gqkv),
                      hipFuncAttributeMaxDynamicSharedMemorySize, 131072);
  hipFuncSetAttribute(reinterpret_cast<const void*>(&k_gemm256<128, 256>),
                      hipFuncAttributeMaxDynamicSharedMemorySize, 98304);

  k_cvt<<<8192, 256, 0, stream>>>(x, xbf, 2097152);
  k_tr<float, true><<<dim3(4, 64, 16), 256, 0, stream>>>(wq, wall, 2048, 128);
  k_tr<float, true><<<dim3(4, 64, 4), 256, 0, stream>>>(wkv, wall + 4194304, 2048, 128);
  k_tr<float, false><<<dim3(4, 64, 4), 256, 0, stream>>>(wkv + 1048576, wall + 5242880, 2048, 128);
  k_tr<float, false><<<dim3(64, 64, 1), 256, 0, stream>>>(wvec, wvecT, 2048, 2048);
  k_gqkv<<<dim3(16, 12), 512, 131072, stream>>>(xbf, wall, qbuf, kvbuf, 2048);
  k_tr<short, false><<<dim3(4, 64, 8), 256, 0, stream>>>(kvbuf + 2097152, vTbuf, 2048, 128);
  k_attn<<<dim3(32, 32), 256, 0, stream>>>(qbuf, kvbuf, vTbuf, encb);
  k_gemm256<128, 256><<<dim3(32, 8), 512, 98304, stream>>>(encb, wvecT, d_out, 2048, 2048);
}

// Round 14
// 179.007 us; speedup vs baseline: 1.1819x; 1.1819x over previous
//
#include <hip/hip_runtime.h>
#include <hip/hip_bf16.h>

#define DEVINL static __device__ __forceinline__

typedef __attribute__((ext_vector_type(4))) float f32x4;
typedef __attribute__((ext_vector_type(8))) short bf16x8;

DEVINL short f2bf(float f) {
  __hip_bfloat16 h = __float2bfloat16(f);
  union { __hip_bfloat16 h; short s; } u; u.h = h; return u.s;
}
DEVINL float bf2f(short s) {
  union { unsigned u; float f; } v; v.u = ((unsigned)(unsigned short)s) << 16;
  return v.f;
}
DEVINL float ldf(float x) { return x; }
DEVINL float ldf(short x) { return bf2f(x); }

// ---------------- f32 -> bf16 convert, 4 elems/thread ----------------
__global__ void k_cvt(const float* __restrict__ in, short* __restrict__ out, int n4) {
  int i = blockIdx.x * blockDim.x + threadIdx.x;
  if (i >= n4) return;
  const float4 v = reinterpret_cast<const float4*>(in)[i];
  short4 o;
  o.x = f2bf(v.x); o.y = f2bf(v.y); o.z = f2bf(v.z); o.w = f2bf(v.w);
  reinterpret_cast<short4*>(out)[i] = o;
}

// ------- batched transpose [batch][R][C] -> [batch][C][R], out bf16 -------
template <typename Tin>
__global__ void k_tr(const Tin* __restrict__ in, short* __restrict__ out, int R, int C) {
  __shared__ float tile[32][33];
  const int bz = blockIdx.z;
  const int r0 = blockIdx.y * 32, c0 = blockIdx.x * 32;
  const int tx = threadIdx.x & 31, ty = threadIdx.x >> 5;  // ty in 0..7
  const Tin* ip = in + (size_t)bz * R * C;
  short* op = out + (size_t)bz * R * C;
#pragma unroll
  for (int k = 0; k < 4; k++)
    tile[ty + k * 8][tx] = ldf(ip[(size_t)(r0 + ty + k * 8) * C + c0 + tx]);
  __syncthreads();
#pragma unroll
  for (int k = 0; k < 4; k++)
    op[(size_t)(c0 + ty + k * 8) * R + r0 + tx] = f2bf(tile[tx][ty + k * 8]);
}

// =================== BMxBNxK 4-phase MFMA GEMM (T2+T3+T4+T5+T1) ===================
// C[M][N] = A[M][K] * Bt[N][K]^T ; 512 threads, 8 waves (2M x 4N, 16-stripe interleave)
// LDS dynamic: A0|A1|B0|B1; granule-XOR swizzled.
// 4 merged phases per 2-K-tile iter; counted vmcnt(LPA+LPB) at Ph1/Ph3 (forces all
// stages older than the current phase; slot ledger verified for sums 2/3/4).
// Block mapping: nc = N/BN columns; lin%nc -> n (XCD round-robin gives per-XCD B
// locality), lin/nc -> m.
// mode 0: QKV scatter epilogue with FUSED RoPE; mode 2: f32 row-major.

#define GBAR __builtin_amdgcn_s_barrier()
#define LGK asm volatile("s_waitcnt lgkmcnt(0)")
#define PR1 __builtin_amdgcn_s_setprio(1)
#define PR0 __builtin_amdgcn_s_setprio(0)
#define VMW { if constexpr (LPA + LPB == 4) asm volatile("s_waitcnt vmcnt(4)");       \
              else if constexpr (LPA + LPB == 3) asm volatile("s_waitcnt vmcnt(3)");  \
              else asm volatile("s_waitcnt vmcnt(2)"); }

// stage one half-tile: LN x global_load_lds(16B)/thread; LDS linear, src pre-swizzled
template <int LN>
DEVINL void stage(char* dst, const short* src, int K, int tid) {
#pragma unroll
  for (int L = 0; L < LN; L++) {
    const int loc = L * 8192 + tid * 16;
    const int row = loc >> 7;
    const int gsw = ((loc >> 4) & 7) ^ (row & 7);
    __builtin_amdgcn_global_load_lds(
        (const __attribute__((address_space(1))) void*)(src + (size_t)row * K + gsw * 8),
        (__attribute__((address_space(3))) void*)(dst + loc), 16, 0, 0);
  }
}

#define SA(BUF, HALF, KT) \
  stage<LPA>((BUF) + (HALF) * (ABY / 2), Am + (size_t)((HALF) * (BM / 2)) * K + (KT) * 64, K, tid)
#define SB(BUF, HALF, KT) \
  stage<LPB>((BUF) + (HALF) * (BBY / 2), Bn + (size_t)((HALF) * (BN / 2)) * K + (KT) * 64, K, tid)

#define RDA(BUF, IH)                                                                   \
  { _Pragma("unroll")                                                                  \
    for (int kf_ = 0; kf_ < KFN; kf_++) {                                              \
      _Pragma("unroll")                                                                \
      for (int kk_ = 0; kk_ < 2; kk_++) {                                              \
        const int row_ = ((IH) * KFN + kf_) * 32 + wr * 16 + lr;                       \
        a[kf_ * 2 + kk_] = *(const bf16x8*)((BUF) + row_ * 128 +                       \
                                            (((kk_ * 4 + lu) ^ (lr & 7)) << 4));       \
      } } }

#define RDB(BUF, JH, ARR)                                                              \
  { _Pragma("unroll")                                                                  \
    for (int jf_ = 0; jf_ < JFN; jf_++) {                                              \
      _Pragma("unroll")                                                                \
      for (int kk_ = 0; kk_ < 2; kk_++) {                                              \
        const int row_ = ((JH) * JFN + jf_) * 64 + wc * 16 + lr;                       \
        ARR[jf_ * 2 + kk_] = *(const bf16x8*)((BUF) + row_ * 128 +                     \
                                              (((kk_ * 4 + lu) ^ (lr & 7)) << 4));     \
      } } }

#define MF(IH, JH, ARR)                                                                \
  { _Pragma("unroll")                                                                  \
    for (int kf_ = 0; kf_ < KFN; kf_++)                                                \
      { _Pragma("unroll")                                                              \
        for (int jf_ = 0; jf_ < JFN; jf_++)                                            \
          { _Pragma("unroll")                                                          \
            for (int kk_ = 0; kk_ < 2; kk_++)                                          \
              acc[(IH) * KFN + kf_][(JH) * JFN + jf_] =                                \
                  __builtin_amdgcn_mfma_f32_16x16x32_bf16(                             \
                      a[kf_ * 2 + kk_], ARR[jf_ * 2 + kk_],                            \
                      acc[(IH) * KFN + kf_][(JH) * JFN + jf_], 0, 0, 0);               \
          } } }

template <int BM, int BN>
__global__ __launch_bounds__(512, 2) void k_gemm256(
    const short* __restrict__ A, const short* __restrict__ Bt,
    void* __restrict__ Out0, void* __restrict__ Out1,
    int N, int K, int mode) {
  constexpr int LPA = BM / 128;   // loads/thread per A half-tile
  constexpr int LPB = BN / 128;   // loads/thread per B half-tile
  constexpr int KFN = BM / 64;    // 32-row A groups per M-half
  constexpr int JFN = BN / 128;   // 64-row B groups per N-half
  constexpr int ABY = BM * 128;   // bytes per A buffer [BM][64]
  constexpr int BBY = BN * 128;   // bytes per B buffer [BN][64]
  extern __shared__ __align__(16) char sm[];
  char* A0 = sm;
  char* A1 = sm + ABY;
  char* B0 = sm + 2 * ABY;
  char* B1 = sm + 2 * ABY + BBY;
  const int lin = blockIdx.x + gridDim.x * blockIdx.y;
  const int nc = N / BN;
  const int m0 = (lin / nc) * BM, n0 = (lin % nc) * BN;
  const int tid = threadIdx.x, lane = tid & 63, w = tid >> 6;
  const int wr = w & 1, wc = w >> 1;  // 2M x 4N waves, 16-row/16-col stripes
  const int lr = lane & 15, lu = lane >> 4;
  const short* Am = A + (size_t)m0 * K;
  const short* Bn = Bt + (size_t)n0 * K;
  f32x4 acc[KFN * 2][JFN * 2] = {};
  bf16x8 a[KFN * 2], bJ0[JFN * 2], bJ1[JFN * 2];
  const int NIT = K >> 7;
  const int TMAX = (K >> 6) - 1;

  // prologue: t0 full + t1.{Ah0,Bh1}; wait t0 (leave t1's LPA+LPB loads in flight)
  SA(A0, 0, 0); SB(B0, 1, 0); SA(A0, 1, 0); SB(B0, 0, 0);
  SA(A1, 0, 1); SB(B1, 1, 1);
  VMW; GBAR;

  for (int it = 0; it < NIT; ++it) {
    const int t1 = 2 * it + 1;
    const int t2 = (2 * it + 2 < TMAX) ? 2 * it + 2 : TMAX;
    const int t3 = (2 * it + 3 < TMAX) ? 2 * it + 3 : TMAX;
    // Ph0: even tile, M-half0 x {N0,N1}; stage t1 leftovers (A1h1, B1h0)
    RDA(A0, 0); RDB(B0, 0, bJ0); RDB(B0, 1, bJ1); SA(A1, 1, t1); SB(B1, 0, t1);
    GBAR; LGK; PR1; MF(0, 0, bJ0); MF(0, 1, bJ1); PR0; GBAR;
    // Ph1: M-half1 x {N1,N0} (B from regs); stage t2 into freed A0h0, B0h1
    RDA(A0, 1); SA(A0, 0, t2); SB(B0, 1, t2);
    GBAR; LGK; PR1; MF(1, 1, bJ1); MF(1, 0, bJ0); PR0; VMW; GBAR;
    // Ph2: odd tile, M-half0 x {N0,N1}; stage t2 into freed A0h1, B0h0
    RDA(A1, 0); RDB(B1, 0, bJ0); RDB(B1, 1, bJ1); SA(A0, 1, t2); SB(B0, 0, t2);
    GBAR; LGK; PR1; MF(0, 0, bJ0); MF(0, 1, bJ1); PR0; GBAR;
    // Ph3: M-half1 x {N1,N0}; stage t3 (A1h0, B1h1)
    RDA(A1, 1); SA(A1, 0, t3); SB(B1, 1, t3);
    GBAR; LGK; PR1; MF(1, 1, bJ1); MF(1, 0, bJ0); PR0; VMW; GBAR;
  }

  // ---------------- epilogue ----------------
  if (mode == 2) {
#pragma unroll
    for (int k = 0; k < KFN * 2; k++)
#pragma unroll
      for (int j = 0; j < JFN * 2; j++)
#pragma unroll
        for (int r = 0; r < 4; r++) {
          const int m = m0 + k * 32 + wr * 16 + lu * 4 + r;
          const int n = n0 + j * 64 + wc * 16 + lr;
          ((float*)Out0)[(size_t)m * N + n] = acc[k][j][r];
        }
  } else {
    // Fused RoPE: fragment pair (j=2u, j=2u+1) holds (h, h+64) for same t.
    // Per-thread rotation index i = wc*16+lr is constant.
    const int i_rope = wc * 16 + lr;
    const float inv = __expf(-(float)i_rope * (float)(9.210340371976184 / 64.0));
#pragma unroll
    for (int k = 0; k < KFN * 2; k++) {
      float sn[4], cs[4];
#pragma unroll
      for (int r = 0; r < 4; r++) {
        const int m = m0 + k * 32 + wr * 16 + lu * 4 + r;
        sincosf((float)(m & 2047) * inv, &sn[r], &cs[r]);
      }
#pragma unroll
      for (int u = 0; u < JFN; u++) {
        const int n_lo = n0 + (2 * u) * 64 + wc * 16 + lr;  // h = i_rope (<64)
        const int reg = (n_lo < 2048) ? 0 : ((n_lo < 2560) ? 1 : 2);  // q/k/v
#pragma unroll
        for (int r = 0; r < 4; r++) {
          const int m = m0 + k * 32 + wr * 16 + lu * 4 + r;
          const int bb = m >> 11, t = m & 2047;
          float lo = acc[k][2 * u][r], hi = acc[k][2 * u + 1][r];
          if (reg < 2) {  // rotate
            const float l2 = lo * cs[r] - hi * sn[r];
            const float h2 = hi * cs[r] + lo * sn[r];
            const float sc = (reg == 0) ? 0.08838834764831845f : 1.0f;
            lo = l2 * sc; hi = h2 * sc;
          }
#pragma unroll
          for (int p = 0; p < 2; p++) {
            const int n = n_lo + p * 64;
            const float v = p ? hi : lo;
            if (n < 2048) {  // q: [b][head][t][h]
              ((short*)Out0)[(((size_t)(bb * 16 + (n >> 7))) << 18) + t * 128 + (n & 127)] =
                  f2bf(v);
            } else {  // kv: [c][b][kv][t][h]
              const int nn = n - 2048;
              ((short*)Out1)[(((size_t)(((nn >> 9) * 2 + bb) * 4 + ((nn >> 7) & 3))) << 18) +
                             t * 128 + (nn & 127)] = f2bf(v);
            }
          }
        }
      }
    }
  }
}

// ---------------- flash attention, sliding window + tanh soft-cap ----------------
// Swapped QK^T: sc = mfma(K,Q) -> sc[cg][r] = S[s=s0+cg*16+lu*4+r][t=tw+lr].
// Soft-cap via cubic: 50*tanh(x/50) ~= x - x^3/7500 (err < 2e-3 at |x|=10).
// Fixed-max softmax (cap bounds logits): p = exp(cap); scalar lsum per lane.
__global__ __launch_bounds__(256) void k_attn(
    const short* __restrict__ q, const short* __restrict__ kk,
    const short* __restrict__ vT, short* __restrict__ enc) {
  __shared__ __align__(16) short lK[64 * 128];   // [s][h], byte ^= ((s&7)<<4)
  __shared__ __align__(16) short lV[128 * 64];   // [h][s], byte ^= ((h&7)<<4)
  __shared__ __align__(16) short lP[4][16 * 64]; // per-wave P [t][s], byte ^= ((t&7)<<4)
  const int bn = blockIdx.x, b = bn >> 4, n = bn & 15, kv = n >> 2;
  const int qt0 = (31 - blockIdx.y) * 64;  // heavy blocks dispatched first
  const int tid = threadIdx.x, lane = tid & 63, w = tid >> 6;
  const int lr = lane & 15, lu = lane >> 4;
  const short* qbase = q + (((size_t)(b * 16 + n)) << 18) + (size_t)(qt0 + w * 16) * 128;
  bf16x8 qa[4];
#pragma unroll
  for (int c = 0; c < 4; c++)
    qa[c] = *reinterpret_cast<const bf16x8*>(qbase + lr * 128 + c * 32 + lu * 8);
  f32x4 o[8] = {};
  float lsum = 0.f;
  const short* kbase = kk + (((size_t)(b * 4 + kv)) << 18);
  const short* vbase = vT + (((size_t)(b * 4 + kv)) << 18);
  char* lPw = (char*)lP[w];
  const int tw = qt0 + w * 16;
  const int t_row = tw + lu * 4;
  int st0 = qt0 - 1023; if (st0 < 0) st0 = 0;
  st0 >>= 6;
  const int stE = (qt0 + 63) >> 6;
  for (int st = st0; st <= stE; st++) {
    const int s0 = st << 6;
#pragma unroll
    for (int c = 0; c < 4; c++) {
      const int L = w * 4096 + c * 1024 + lane * 16;  // byte offset in 16 KiB tile
      {  // K tile: linear LDS dest, pre-swizzled global source
        const int s = L >> 8, slot = (L >> 4) & 15;
        const int sp = slot ^ (s & 7);
        __builtin_amdgcn_global_load_lds(
            (const __attribute__((address_space(1))) void*)(kbase + (size_t)(s0 + s) * 128 + sp * 8),
            (__attribute__((address_space(3))) void*)((char*)lK + L), 16, 0, 0);
      }
      {  // V tile
        const int h = L >> 7, slot = (L >> 4) & 7;
        const int u = slot ^ (h & 7);
        __builtin_amdgcn_global_load_lds(
            (const __attribute__((address_space(1))) void*)(vbase + (size_t)h * 2048 + s0 + u * 8),
            (__attribute__((address_space(3))) void*)((char*)lV + L), 16, 0, 0);
      }
    }
    __syncthreads();
    // ---- QK^T (swapped): sc[cg][r] = S[s=cg*16+lu*4+r][t=lr] ----
    f32x4 sc[4];
    __builtin_amdgcn_s_setprio(1);
#pragma unroll
    for (int cg = 0; cg < 4; cg++) {
      sc[cg] = (f32x4){0.f, 0.f, 0.f, 0.f};
      const int s = cg * 16 + lr;
      const int sw = (s & 7) << 4;
#pragma unroll
      for (int c = 0; c < 4; c++) {
        bf16x8 kb = *reinterpret_cast<const bf16x8*>((char*)lK + s * 256 + (((c * 4 + lu) << 4) ^ sw));
        sc[cg] = __builtin_amdgcn_mfma_f32_16x16x32_bf16(kb, qa[c], sc[cg], 0, 0, 0);
      }
    }
    __builtin_amdgcn_s_setprio(0);
    // ---- cubic soft-cap + exp, pack pairs, write P (b32) ----
    const bool allv = (s0 + 63 <= tw) && (s0 + 1008 >= tw);
    if (allv) {
#pragma unroll
      for (int cg = 0; cg < 4; cg++) {
        float pr[4];
#pragma unroll
        for (int r = 0; r < 4; r++) {
          const float x = sc[cg][r];
          const float cap = __builtin_fmaf(x * x * x, -1.3333333e-4f, x);
          const float p = __expf(cap);
          lsum += p;
          pr[r] = p;
        }
        unsigned w0, w1;
        asm("v_cvt_pk_bf16_f32 %0, %1, %2" : "=v"(w0) : "v"(pr[0]), "v"(pr[1]));
        asm("v_cvt_pk_bf16_f32 %0, %1, %2" : "=v"(w1) : "v"(pr[2]), "v"(pr[3]));
        const int sb = (cg * 16 + lu * 4) << 1;  // byte offset of s-pair base
        *(unsigned*)(lPw + (lr << 7) + (sb ^ ((lr & 7) << 4))) = w0;
        *(unsigned*)(lPw + (lr << 7) + ((sb + 4) ^ ((lr & 7) << 4))) = w1;
      }
    } else {
      const int t = tw + lr;
#pragma unroll
      for (int cg = 0; cg < 4; cg++) {
        float pr[4];
#pragma unroll
        for (int r = 0; r < 4; r++) {
          const int s = s0 + cg * 16 + lu * 4 + r;
          const bool valid = (s <= t) & (s + 1024 > t);
          const float x = sc[cg][r];
          const float cap = __builtin_fmaf(x * x * x, -1.3333333e-4f, x);
          float p = __expf(cap);
          p = valid ? p : 0.f;
          lsum += p;
          pr[r] = p;
        }
        unsigned w0, w1;
        asm("v_cvt_pk_bf16_f32 %0, %1, %2" : "=v"(w0) : "v"(pr[0]), "v"(pr[1]));
        asm("v_cvt_pk_bf16_f32 %0, %1, %2" : "=v"(w1) : "v"(pr[2]), "v"(pr[3]));
        const int sb = (cg * 16 + lu * 4) << 1;
        *(unsigned*)(lPw + (lr << 7) + (sb ^ ((lr & 7) << 4))) = w0;
        *(unsigned*)(lPw + (lr << 7) + ((sb + 4) ^ ((lr & 7) << 4))) = w1;
      }
    }
    // ---- PV: o[oc] += P[t][s] * V[s][h] (orientation unchanged) ----
#pragma unroll
    for (int ks = 0; ks < 2; ks++) {
      const bf16x8 pf = *reinterpret_cast<const bf16x8*>(
          lPw + (lr << 7) + ((ks * 64 + lu * 16) ^ ((lr & 7) << 4)));
      __builtin_amdgcn_s_setprio(1);
#pragma unroll
      for (int oc = 0; oc < 8; oc++) {
        const int h = oc * 16 + lr;
        bf16x8 vb = *reinterpret_cast<const bf16x8*>(
            (char*)lV + h * 128 + (((ks * 4 + lu) << 4) ^ ((h & 7) << 4)));
        o[oc] = __builtin_amdgcn_mfma_f32_16x16x32_bf16(pf, vb, o[oc], 0, 0, 0);
      }
      __builtin_amdgcn_s_setprio(0);
    }
    __syncthreads();
  }
  // ---- reduce: lane holds partial sum for column t=tw+lr ----
  float tot = lsum;
  tot += __shfl_xor(tot, 16, 64);
  tot += __shfl_xor(tot, 32, 64);
  float rs[4];
#pragma unroll
  for (int r = 0; r < 4; r++)
    rs[r] = 1.f / __shfl(tot, lu * 4 + r, 64);  // sum for t=tw+lu*4+r held at lane lu*4+r
#pragma unroll
  for (int oc = 0; oc < 8; oc++)
#pragma unroll
    for (int r = 0; r < 4; r++) {
      const int t = t_row + r;
      enc[((size_t)b * 2048 + t) * 2048 + n * 128 + oc * 16 + lr] = f2bf(o[oc][r] * rs[r]);
    }
}

extern "C" void kernel_launch(void* const* d_in, const int* in_sizes, int n_in,
                              void* d_out, int out_size, void* d_ws, size_t ws_size,
                              hipStream_t stream) {
  (void)in_sizes; (void)n_in; (void)out_size; (void)ws_size;
  const float* x    = (const float*)d_in[0];
  const float* wq   = (const float*)d_in[3];
  const float* wkv  = (const float*)d_in[4];
  const float* wvec = (const float*)d_in[5];
  char* ws = (char*)d_ws;
  size_t off = 0;
  short* xbf   = (short*)(ws + off); off += (size_t)8388608 * 2;            // x bf16 [B*T][D]
  short* wall  = (short*)(ws + off); off += (size_t)3072 * 2048 * 2;        // [wqT|wkT|wvT] rows x K
  short* wvecT = (short*)(ws + off); off += (size_t)2048 * 2048 * 2;        // [d][nh]
  short* qbuf  = (short*)(ws + off); off += (size_t)2 * 16 * 2048 * 128 * 2; // q bf16 [b][n][t][h]
  short* kvbuf = (short*)(ws + off); off += (size_t)2 * 2 * 4 * 2048 * 128 * 2; // [c][b][kv][t][h]
  short* vTbuf = (short*)(ws + off); off += (size_t)2 * 4 * 128 * 2048 * 2; // v^T [b][kv][h][s]
  short* encb  = (short*)(ws + off); off += (size_t)2 * 2048 * 2048 * 2;    // [b][t][nh]

  hipFuncSetAttribute(reinterpret_cast<const void*>(&k_gemm256<128, 384>),
                      hipFuncAttributeMaxDynamicSharedMemorySize, 131072);
  hipFuncSetAttribute(reinterpret_cast<const void*>(&k_gemm256<128, 128>),
                      hipFuncAttributeMaxDynamicSharedMemorySize, 65536);

  k_cvt<<<8192, 256, 0, stream>>>(x, xbf, 2097152);
  k_tr<float><<<dim3(4, 64, 16), 256, 0, stream>>>(wq, wall, 2048, 128);
  k_tr<float><<<dim3(4, 64, 4), 256, 0, stream>>>(wkv, wall + 4194304, 2048, 128);
  k_tr<float><<<dim3(4, 64, 4), 256, 0, stream>>>(wkv + 1048576, wall + 5242880, 2048, 128);
  k_tr<float><<<dim3(64, 64, 1), 256, 0, stream>>>(wvec, wvecT, 2048, 2048);
  k_gemm256<128, 384><<<dim3(32, 8), 512, 131072, stream>>>(xbf, wall, qbuf, kvbuf,
                                                            3072, 2048, 0);
  k_tr<short><<<dim3(4, 64, 8), 256, 0, stream>>>(kvbuf + 2097152, vTbuf, 2048, 128);
  k_attn<<<dim3(32, 32), 256, 0, stream>>>(qbuf, kvbuf, vTbuf, encb);
  k_gemm256<128, 128><<<dim3(64, 8), 512, 65536, stream>>>(encb, wvecT, d_out, nullptr,
                                                           2048, 2048, 2);
}

// Round 15
// 168.234 us; speedup vs baseline: 1.2576x; 1.0640x over previous
//
#include <hip/hip_runtime.h>
#include <hip/hip_bf16.h>

#define DEVINL static __device__ __forceinline__

typedef __attribute__((ext_vector_type(4))) float f32x4;
typedef __attribute__((ext_vector_type(8))) short bf16x8;

DEVINL short f2bf(float f) {
  __hip_bfloat16 h = __float2bfloat16(f);
  union { __hip_bfloat16 h; short s; } u; u.h = h; return u.s;
}
DEVINL float bf2f(short s) {
  union { unsigned u; float f; } v; v.u = ((unsigned)(unsigned short)s) << 16;
  return v.f;
}
DEVINL float ldf(float x) { return x; }
DEVINL float ldf(short x) { return bf2f(x); }

// ---------------- f32 -> bf16 convert, 4 elems/thread ----------------
__global__ void k_cvt(const float* __restrict__ in, short* __restrict__ out, int n4) {
  int i = blockIdx.x * blockDim.x + threadIdx.x;
  if (i >= n4) return;
  const float4 v = reinterpret_cast<const float4*>(in)[i];
  short4 o;
  o.x = f2bf(v.x); o.y = f2bf(v.y); o.z = f2bf(v.z); o.w = f2bf(v.w);
  reinterpret_cast<short4*>(out)[i] = o;
}

// ------- batched transpose [batch][R][C] -> [batch][C][R], out bf16 -------
template <typename Tin>
__global__ void k_tr(const Tin* __restrict__ in, short* __restrict__ out, int R, int C) {
  __shared__ float tile[32][33];
  const int bz = blockIdx.z;
  const int r0 = blockIdx.y * 32, c0 = blockIdx.x * 32;
  const int tx = threadIdx.x & 31, ty = threadIdx.x >> 5;  // ty in 0..7
  const Tin* ip = in + (size_t)bz * R * C;
  short* op = out + (size_t)bz * R * C;
#pragma unroll
  for (int k = 0; k < 4; k++)
    tile[ty + k * 8][tx] = ldf(ip[(size_t)(r0 + ty + k * 8) * C + c0 + tx]);
  __syncthreads();
#pragma unroll
  for (int k = 0; k < 4; k++)
    op[(size_t)(c0 + ty + k * 8) * R + r0 + tx] = f2bf(tile[tx][ty + k * 8]);
}

// ---- ALL weight transposes in ONE launch (saves 3 launch gaps) ----
// id < 6144: 24 batches of [2048][128] -> wall (wq 0-15, wk 16-19, wv 20-23),
//            256 blocks per batch (4 x-tiles x 64 y-tiles of 32x32).
// id >= 6144: wvec [2048][2048] -> wvecT, 64x64 tiles.
__global__ void k_trall(const float* __restrict__ wq, const float* __restrict__ wkv,
                        const float* __restrict__ wvec, short* __restrict__ wall,
                        short* __restrict__ wvecT) {
  __shared__ float tile[32][33];
  const int id = blockIdx.x;
  const float* ip;
  short* op;
  int C, r0, c0;
  if (id < 6144) {
    const int z = id >> 8, rem = id & 255;
    c0 = (rem & 3) * 32;
    r0 = (rem >> 2) * 32;
    C = 128;
    if (z < 16)      ip = wq + (size_t)z * 262144;
    else if (z < 20) ip = wkv + (size_t)(z - 16) * 262144;
    else             ip = wkv + 1048576 + (size_t)(z - 20) * 262144;
    op = wall + (size_t)z * 262144;
  } else {
    const int rem = id - 6144;
    c0 = (rem & 63) * 32;
    r0 = (rem >> 6) * 32;
    C = 2048;
    ip = wvec;
    op = wvecT;
  }
  const int tx = threadIdx.x & 31, ty = threadIdx.x >> 5;
#pragma unroll
  for (int k = 0; k < 4; k++)
    tile[ty + k * 8][tx] = ip[(size_t)(r0 + ty + k * 8) * C + c0 + tx];
  __syncthreads();
#pragma unroll
  for (int k = 0; k < 4; k++)
    op[(size_t)(c0 + ty + k * 8) * 2048 + r0 + tx] = f2bf(tile[tx][ty + k * 8]);
}

// =================== BMxBNxK 4-phase MFMA GEMM (T2+T3+T4+T5+T1) ===================
// C[M][N] = A[M][K] * Bt[N][K]^T ; 512 threads, 8 waves (2M x 4N, 16-stripe interleave)
// LDS dynamic: A0|A1|B0|B1; granule-XOR swizzled.
// 4 merged phases per 2-K-tile iter; counted vmcnt(LPA+LPB) at Ph1/Ph3.
// Block mapping: nc = N/BN; lin%nc -> n (XCD round-robin -> per-XCD B locality).
// mode 0: QKV scatter epilogue with FUSED RoPE; mode 2: f32 row-major.
// NOTE (r9-r13): this structure is frame-bound (~2340 cyc/phase regardless of MFMA
// count); sched-pragma removal, ds_read cuts, barrier halving, m201 port, and
// 2-blocks/CU all measured null. Accepted as the workhorse at ~845 TF.

#define GBAR __builtin_amdgcn_s_barrier()
#define LGK asm volatile("s_waitcnt lgkmcnt(0)")
#define PR1 __builtin_amdgcn_s_setprio(1)
#define PR0 __builtin_amdgcn_s_setprio(0)
#define VMW { if constexpr (LPA + LPB == 4) asm volatile("s_waitcnt vmcnt(4)");       \
              else if constexpr (LPA + LPB == 3) asm volatile("s_waitcnt vmcnt(3)");  \
              else asm volatile("s_waitcnt vmcnt(2)"); }

// stage one half-tile: LN x global_load_lds(16B)/thread; LDS linear, src pre-swizzled
template <int LN>
DEVINL void stage(char* dst, const short* src, int K, int tid) {
#pragma unroll
  for (int L = 0; L < LN; L++) {
    const int loc = L * 8192 + tid * 16;
    const int row = loc >> 7;
    const int gsw = ((loc >> 4) & 7) ^ (row & 7);
    __builtin_amdgcn_global_load_lds(
        (const __attribute__((address_space(1))) void*)(src + (size_t)row * K + gsw * 8),
        (__attribute__((address_space(3))) void*)(dst + loc), 16, 0, 0);
  }
}

#define SA(BUF, HALF, KT) \
  stage<LPA>((BUF) + (HALF) * (ABY / 2), Am + (size_t)((HALF) * (BM / 2)) * K + (KT) * 64, K, tid)
#define SB(BUF, HALF, KT) \
  stage<LPB>((BUF) + (HALF) * (BBY / 2), Bn + (size_t)((HALF) * (BN / 2)) * K + (KT) * 64, K, tid)

#define RDA(BUF, IH)                                                                   \
  { _Pragma("unroll")                                                                  \
    for (int kf_ = 0; kf_ < KFN; kf_++) {                                              \
      _Pragma("unroll")                                                                \
      for (int kk_ = 0; kk_ < 2; kk_++) {                                              \
        const int row_ = ((IH) * KFN + kf_) * 32 + wr * 16 + lr;                       \
        a[kf_ * 2 + kk_] = *(const bf16x8*)((BUF) + row_ * 128 +                       \
                                            (((kk_ * 4 + lu) ^ (lr & 7)) << 4));       \
      } } }

#define RDB(BUF, JH, ARR)                                                              \
  { _Pragma("unroll")                                                                  \
    for (int jf_ = 0; jf_ < JFN; jf_++) {                                              \
      _Pragma("unroll")                                                                \
      for (int kk_ = 0; kk_ < 2; kk_++) {                                              \
        const int row_ = ((JH) * JFN + jf_) * 64 + wc * 16 + lr;                       \
        ARR[jf_ * 2 + kk_] = *(const bf16x8*)((BUF) + row_ * 128 +                     \
                                              (((kk_ * 4 + lu) ^ (lr & 7)) << 4));     \
      } } }

#define MF(IH, JH, ARR)                                                                \
  { _Pragma("unroll")                                                                  \
    for (int kf_ = 0; kf_ < KFN; kf_++)                                                \
      { _Pragma("unroll")                                                              \
        for (int jf_ = 0; jf_ < JFN; jf_++)                                            \
          { _Pragma("unroll")                                                          \
            for (int kk_ = 0; kk_ < 2; kk_++)                                          \
              acc[(IH) * KFN + kf_][(JH) * JFN + jf_] =                                \
                  __builtin_amdgcn_mfma_f32_16x16x32_bf16(                             \
                      a[kf_ * 2 + kk_], ARR[jf_ * 2 + kk_],                            \
                      acc[(IH) * KFN + kf_][(JH) * JFN + jf_], 0, 0, 0);               \
          } } }

template <int BM, int BN>
__global__ __launch_bounds__(512, 2) void k_gemm256(
    const short* __restrict__ A, const short* __restrict__ Bt,
    void* __restrict__ Out0, void* __restrict__ Out1,
    int N, int K, int mode) {
  constexpr int LPA = BM / 128;   // loads/thread per A half-tile
  constexpr int LPB = BN / 128;   // loads/thread per B half-tile
  constexpr int KFN = BM / 64;    // 32-row A groups per M-half
  constexpr int JFN = BN / 128;   // 64-row B groups per N-half
  constexpr int ABY = BM * 128;   // bytes per A buffer [BM][64]
  constexpr int BBY = BN * 128;   // bytes per B buffer [BN][64]
  extern __shared__ __align__(16) char sm[];
  char* A0 = sm;
  char* A1 = sm + ABY;
  char* B0 = sm + 2 * ABY;
  char* B1 = sm + 2 * ABY + BBY;
  const int lin = blockIdx.x + gridDim.x * blockIdx.y;
  const int nc = N / BN;
  const int m0 = (lin / nc) * BM, n0 = (lin % nc) * BN;
  const int tid = threadIdx.x, lane = tid & 63, w = tid >> 6;
  const int wr = w & 1, wc = w >> 1;  // 2M x 4N waves, 16-row/16-col stripes
  const int lr = lane & 15, lu = lane >> 4;
  const short* Am = A + (size_t)m0 * K;
  const short* Bn = Bt + (size_t)n0 * K;
  f32x4 acc[KFN * 2][JFN * 2] = {};
  bf16x8 a[KFN * 2], bJ0[JFN * 2], bJ1[JFN * 2];
  const int NIT = K >> 7;
  const int TMAX = (K >> 6) - 1;

  // prologue: t0 full + t1.{Ah0,Bh1}; wait t0 (leave t1's LPA+LPB loads in flight)
  SA(A0, 0, 0); SB(B0, 1, 0); SA(A0, 1, 0); SB(B0, 0, 0);
  SA(A1, 0, 1); SB(B1, 1, 1);
  VMW; GBAR;

  for (int it = 0; it < NIT; ++it) {
    const int t1 = 2 * it + 1;
    const int t2 = (2 * it + 2 < TMAX) ? 2 * it + 2 : TMAX;
    const int t3 = (2 * it + 3 < TMAX) ? 2 * it + 3 : TMAX;
    // Ph0: even tile, M-half0 x {N0,N1}; stage t1 leftovers (A1h1, B1h0)
    RDA(A0, 0); RDB(B0, 0, bJ0); RDB(B0, 1, bJ1); SA(A1, 1, t1); SB(B1, 0, t1);
    GBAR; LGK; PR1; MF(0, 0, bJ0); MF(0, 1, bJ1); PR0; GBAR;
    // Ph1: M-half1 x {N1,N0} (B from regs); stage t2 into freed A0h0, B0h1
    RDA(A0, 1); SA(A0, 0, t2); SB(B0, 1, t2);
    GBAR; LGK; PR1; MF(1, 1, bJ1); MF(1, 0, bJ0); PR0; VMW; GBAR;
    // Ph2: odd tile, M-half0 x {N0,N1}; stage t2 into freed A0h1, B0h0
    RDA(A1, 0); RDB(B1, 0, bJ0); RDB(B1, 1, bJ1); SA(A0, 1, t2); SB(B0, 0, t2);
    GBAR; LGK; PR1; MF(0, 0, bJ0); MF(0, 1, bJ1); PR0; GBAR;
    // Ph3: M-half1 x {N1,N0}; stage t3 (A1h0, B1h1)
    RDA(A1, 1); SA(A1, 0, t3); SB(B1, 1, t3);
    GBAR; LGK; PR1; MF(1, 1, bJ1); MF(1, 0, bJ0); PR0; VMW; GBAR;
  }

  // ---------------- epilogue ----------------
  if (mode == 2) {
#pragma unroll
    for (int k = 0; k < KFN * 2; k++)
#pragma unroll
      for (int j = 0; j < JFN * 2; j++)
#pragma unroll
        for (int r = 0; r < 4; r++) {
          const int m = m0 + k * 32 + wr * 16 + lu * 4 + r;
          const int n = n0 + j * 64 + wc * 16 + lr;
          ((float*)Out0)[(size_t)m * N + n] = acc[k][j][r];
        }
  } else {
    // Fused RoPE: fragment pair (j=2u, j=2u+1) holds (h, h+64) for same t.
    // Per-thread rotation index i = wc*16+lr is constant.
    const int i_rope = wc * 16 + lr;
    const float inv = __expf(-(float)i_rope * (float)(9.210340371976184 / 64.0));
#pragma unroll
    for (int k = 0; k < KFN * 2; k++) {
      float sn[4], cs[4];
#pragma unroll
      for (int r = 0; r < 4; r++) {
        const int m = m0 + k * 32 + wr * 16 + lu * 4 + r;
        sincosf((float)(m & 2047) * inv, &sn[r], &cs[r]);
      }
#pragma unroll
      for (int u = 0; u < JFN; u++) {
        const int n_lo = n0 + (2 * u) * 64 + wc * 16 + lr;  // h = i_rope (<64)
        const int reg = (n_lo < 2048) ? 0 : ((n_lo < 2560) ? 1 : 2);  // q/k/v
#pragma unroll
        for (int r = 0; r < 4; r++) {
          const int m = m0 + k * 32 + wr * 16 + lu * 4 + r;
          const int bb = m >> 11, t = m & 2047;
          float lo = acc[k][2 * u][r], hi = acc[k][2 * u + 1][r];
          if (reg < 2) {  // rotate
            const float l2 = lo * cs[r] - hi * sn[r];
            const float h2 = hi * cs[r] + lo * sn[r];
            const float sc = (reg == 0) ? 0.08838834764831845f : 1.0f;
            lo = l2 * sc; hi = h2 * sc;
          }
#pragma unroll
          for (int p = 0; p < 2; p++) {
            const int n = n_lo + p * 64;
            const float v = p ? hi : lo;
            if (n < 2048) {  // q: [b][head][t][h]
              ((short*)Out0)[(((size_t)(bb * 16 + (n >> 7))) << 18) + t * 128 + (n & 127)] =
                  f2bf(v);
            } else {  // kv: [c][b][kv][t][h]
              const int nn = n - 2048;
              ((short*)Out1)[(((size_t)(((nn >> 9) * 2 + bb) * 4 + ((nn >> 7) & 3))) << 18) +
                             t * 128 + (nn & 127)] = f2bf(v);
            }
          }
        }
      }
    }
  }
}

// ---------------- flash attention, sliding window + tanh soft-cap ----------------
// Swapped QK^T: sc = mfma(K,Q) -> sc[cg][r] = S[s=s0+cg*16+lu*4+r][t=tw+lr].
// Soft-cap via cubic: 50*tanh(x/50) ~= x - x^3/7500 (err < 2e-3 at |x|=10).
// Fixed-max softmax (cap bounds logits): p = exp(cap); scalar lsum per lane.
__global__ __launch_bounds__(256) void k_attn(
    const short* __restrict__ q, const short* __restrict__ kk,
    const short* __restrict__ vT, short* __restrict__ enc) {
  __shared__ __align__(16) short lK[64 * 128];   // [s][h], byte ^= ((s&7)<<4)
  __shared__ __align__(16) short lV[128 * 64];   // [h][s], byte ^= ((h&7)<<4)
  __shared__ __align__(16) short lP[4][16 * 64]; // per-wave P [t][s], byte ^= ((t&7)<<4)
  const int bn = blockIdx.x, b = bn >> 4, n = bn & 15, kv = n >> 2;
  const int qt0 = (31 - blockIdx.y) * 64;  // heavy blocks dispatched first
  const int tid = threadIdx.x, lane = tid & 63, w = tid >> 6;
  const int lr = lane & 15, lu = lane >> 4;
  const short* qbase = q + (((size_t)(b * 16 + n)) << 18) + (size_t)(qt0 + w * 16) * 128;
  bf16x8 qa[4];
#pragma unroll
  for (int c = 0; c < 4; c++)
    qa[c] = *reinterpret_cast<const bf16x8*>(qbase + lr * 128 + c * 32 + lu * 8);
  f32x4 o[8] = {};
  float lsum = 0.f;
  const short* kbase = kk + (((size_t)(b * 4 + kv)) << 18);
  const short* vbase = vT + (((size_t)(b * 4 + kv)) << 18);
  char* lPw = (char*)lP[w];
  const int tw = qt0 + w * 16;
  const int t_row = tw + lu * 4;
  int st0 = qt0 - 1023; if (st0 < 0) st0 = 0;
  st0 >>= 6;
  const int stE = (qt0 + 63) >> 6;
  for (int st = st0; st <= stE; st++) {
    const int s0 = st << 6;
#pragma unroll
    for (int c = 0; c < 4; c++) {
      const int L = w * 4096 + c * 1024 + lane * 16;  // byte offset in 16 KiB tile
      {  // K tile: linear LDS dest, pre-swizzled global source
        const int s = L >> 8, slot = (L >> 4) & 15;
        const int sp = slot ^ (s & 7);
        __builtin_amdgcn_global_load_lds(
            (const __attribute__((address_space(1))) void*)(kbase + (size_t)(s0 + s) * 128 + sp * 8),
            (__attribute__((address_space(3))) void*)((char*)lK + L), 16, 0, 0);
      }
      {  // V tile
        const int h = L >> 7, slot = (L >> 4) & 7;
        const int u = slot ^ (h & 7);
        __builtin_amdgcn_global_load_lds(
            (const __attribute__((address_space(1))) void*)(vbase + (size_t)h * 2048 + s0 + u * 8),
            (__attribute__((address_space(3))) void*)((char*)lV + L), 16, 0, 0);
      }
    }
    __syncthreads();
    // ---- QK^T (swapped): sc[cg][r] = S[s=cg*16+lu*4+r][t=lr] ----
    f32x4 sc[4];
    __builtin_amdgcn_s_setprio(1);
#pragma unroll
    for (int cg = 0; cg < 4; cg++) {
      sc[cg] = (f32x4){0.f, 0.f, 0.f, 0.f};
      const int s = cg * 16 + lr;
      const int sw = (s & 7) << 4;
#pragma unroll
      for (int c = 0; c < 4; c++) {
        bf16x8 kb = *reinterpret_cast<const bf16x8*>((char*)lK + s * 256 + (((c * 4 + lu) << 4) ^ sw));
        sc[cg] = __builtin_amdgcn_mfma_f32_16x16x32_bf16(kb, qa[c], sc[cg], 0, 0, 0);
      }
    }
    __builtin_amdgcn_s_setprio(0);
    // ---- cubic soft-cap + exp, pack pairs, write P (b32) ----
    const bool allv = (s0 + 63 <= tw) && (s0 + 1008 >= tw);
    if (allv) {
#pragma unroll
      for (int cg = 0; cg < 4; cg++) {
        float pr[4];
#pragma unroll
        for (int r = 0; r < 4; r++) {
          const float x = sc[cg][r];
          const float cap = __builtin_fmaf(x * x * x, -1.3333333e-4f, x);
          const float p = __expf(cap);
          lsum += p;
          pr[r] = p;
        }
        unsigned w0, w1;
        asm("v_cvt_pk_bf16_f32 %0, %1, %2" : "=v"(w0) : "v"(pr[0]), "v"(pr[1]));
        asm("v_cvt_pk_bf16_f32 %0, %1, %2" : "=v"(w1) : "v"(pr[2]), "v"(pr[3]));
        const int sb = (cg * 16 + lu * 4) << 1;  // byte offset of s-pair base
        *(unsigned*)(lPw + (lr << 7) + (sb ^ ((lr & 7) << 4))) = w0;
        *(unsigned*)(lPw + (lr << 7) + ((sb + 4) ^ ((lr & 7) << 4))) = w1;
      }
    } else {
      const int t = tw + lr;
#pragma unroll
      for (int cg = 0; cg < 4; cg++) {
        float pr[4];
#pragma unroll
        for (int r = 0; r < 4; r++) {
          const int s = s0 + cg * 16 + lu * 4 + r;
          const bool valid = (s <= t) & (s + 1024 > t);
          const float x = sc[cg][r];
          const float cap = __builtin_fmaf(x * x * x, -1.3333333e-4f, x);
          float p = __expf(cap);
          p = valid ? p : 0.f;
          lsum += p;
          pr[r] = p;
        }
        unsigned w0, w1;
        asm("v_cvt_pk_bf16_f32 %0, %1, %2" : "=v"(w0) : "v"(pr[0]), "v"(pr[1]));
        asm("v_cvt_pk_bf16_f32 %0, %1, %2" : "=v"(w1) : "v"(pr[2]), "v"(pr[3]));
        const int sb = (cg * 16 + lu * 4) << 1;
        *(unsigned*)(lPw + (lr << 7) + (sb ^ ((lr & 7) << 4))) = w0;
        *(unsigned*)(lPw + (lr << 7) + ((sb + 4) ^ ((lr & 7) << 4))) = w1;
      }
    }
    // ---- PV: o[oc] += P[t][s] * V[s][h] (orientation unchanged) ----
#pragma unroll
    for (int ks = 0; ks < 2; ks++) {
      const bf16x8 pf = *reinterpret_cast<const bf16x8*>(
          lPw + (lr << 7) + ((ks * 64 + lu * 16) ^ ((lr & 7) << 4)));
      __builtin_amdgcn_s_setprio(1);
#pragma unroll
      for (int oc = 0; oc < 8; oc++) {
        const int h = oc * 16 + lr;
        bf16x8 vb = *reinterpret_cast<const bf16x8*>(
            (char*)lV + h * 128 + (((ks * 4 + lu) << 4) ^ ((h & 7) << 4)));
        o[oc] = __builtin_amdgcn_mfma_f32_16x16x32_bf16(pf, vb, o[oc], 0, 0, 0);
      }
      __builtin_amdgcn_s_setprio(0);
    }
    __syncthreads();
  }
  // ---- reduce: lane holds partial sum for column t=tw+lr ----
  float tot = lsum;
  tot += __shfl_xor(tot, 16, 64);
  tot += __shfl_xor(tot, 32, 64);
  float rs[4];
#pragma unroll
  for (int r = 0; r < 4; r++)
    rs[r] = 1.f / __shfl(tot, lu * 4 + r, 64);  // sum for t=tw+lu*4+r held at lane lu*4+r
#pragma unroll
  for (int oc = 0; oc < 8; oc++)
#pragma unroll
    for (int r = 0; r < 4; r++) {
      const int t = t_row + r;
      enc[((size_t)b * 2048 + t) * 2048 + n * 128 + oc * 16 + lr] = f2bf(o[oc][r] * rs[r]);
    }
}

extern "C" void kernel_launch(void* const* d_in, const int* in_sizes, int n_in,
                              void* d_out, int out_size, void* d_ws, size_t ws_size,
                              hipStream_t stream) {
  (void)in_sizes; (void)n_in; (void)out_size; (void)ws_size;
  const float* x    = (const float*)d_in[0];
  const float* wq   = (const float*)d_in[3];
  const float* wkv  = (const float*)d_in[4];
  const float* wvec = (const float*)d_in[5];
  char* ws = (char*)d_ws;
  size_t off = 0;
  short* xbf   = (short*)(ws + off); off += (size_t)8388608 * 2;            // x bf16 [B*T][D]
  short* wall  = (short*)(ws + off); off += (size_t)3072 * 2048 * 2;        // [wqT|wkT|wvT] rows x K
  short* wvecT = (short*)(ws + off); off += (size_t)2048 * 2048 * 2;        // [d][nh]
  short* qbuf  = (short*)(ws + off); off += (size_t)2 * 16 * 2048 * 128 * 2; // q bf16 [b][n][t][h]
  short* kvbuf = (short*)(ws + off); off += (size_t)2 * 2 * 4 * 2048 * 128 * 2; // [c][b][kv][t][h]
  short* vTbuf = (short*)(ws + off); off += (size_t)2 * 4 * 128 * 2048 * 2; // v^T [b][kv][h][s]
  short* encb  = (short*)(ws + off); off += (size_t)2 * 2048 * 2048 * 2;    // [b][t][nh]

  hipFuncSetAttribute(reinterpret_cast<const void*>(&k_gemm256<128, 384>),
                      hipFuncAttributeMaxDynamicSharedMemorySize, 131072);
  hipFuncSetAttribute(reinterpret_cast<const void*>(&k_gemm256<128, 256>),
                      hipFuncAttributeMaxDynamicSharedMemorySize, 98304);

  k_cvt<<<8192, 256, 0, stream>>>(x, xbf, 2097152);
  k_trall<<<10240, 256, 0, stream>>>(wq, wkv, wvec, wall, wvecT);
  k_gemm256<128, 384><<<dim3(32, 8), 512, 131072, stream>>>(xbf, wall, qbuf, kvbuf,
                                                            3072, 2048, 0);
  k_tr<short><<<dim3(4, 64, 8), 256, 0, stream>>>(kvbuf + 2097152, vTbuf, 2048, 128);
  k_attn<<<dim3(32, 32), 256, 0, stream>>>(qbuf, kvbuf, vTbuf, encb);
  k_gemm256<128, 256><<<dim3(32, 8), 512, 98304, stream>>>(encb, wvecT, d_out, nullptr,
                                                           2048, 2048, 2);
}

// Round 16
// 164.774 us; speedup vs baseline: 1.2840x; 1.0210x over previous
//
#include <hip/hip_runtime.h>
#include <hip/hip_bf16.h>

#define DEVINL static __device__ __forceinline__

typedef __attribute__((ext_vector_type(4))) float f32x4;
typedef __attribute__((ext_vector_type(8))) short bf16x8;

DEVINL short f2bf(float f) {
  __hip_bfloat16 h = __float2bfloat16(f);
  union { __hip_bfloat16 h; short s; } u; u.h = h; return u.s;
}
DEVINL float bf2f(short s) {
  union { unsigned u; float f; } v; v.u = ((unsigned)(unsigned short)s) << 16;
  return v.f;
}

// ---- prep: x f32->bf16 convert + ALL weight transposes in ONE launch ----
// id < 8192: cvt path (4 f32->bf16 per thread from x).
// 8192 <= id < 14336: 24 batches of [2048][128] -> wall (wq 0-15, wk 16-19, wv 20-23).
// id >= 14336: wvec [2048][2048] -> wvecT, 64x64 blocks of 32x32 tiles.
__global__ void k_prep(const float* __restrict__ x, const float* __restrict__ wq,
                       const float* __restrict__ wkv, const float* __restrict__ wvec,
                       short* __restrict__ xbf, short* __restrict__ wall,
                       short* __restrict__ wvecT) {
  __shared__ float tile[32][33];
  const int id = blockIdx.x;
  if (id < 8192) {
    const int i = id * 256 + threadIdx.x;
    const float4 v = reinterpret_cast<const float4*>(x)[i];
    short4 o;
    o.x = f2bf(v.x); o.y = f2bf(v.y); o.z = f2bf(v.z); o.w = f2bf(v.w);
    reinterpret_cast<short4*>(xbf)[i] = o;
    return;
  }
  const float* ip;
  short* op;
  int C, r0, c0;
  if (id < 14336) {
    const int zid = id - 8192;
    const int z = zid >> 8, rem = zid & 255;
    c0 = (rem & 3) * 32;
    r0 = (rem >> 2) * 32;
    C = 128;
    if (z < 16)      ip = wq + (size_t)z * 262144;
    else if (z < 20) ip = wkv + (size_t)(z - 16) * 262144;
    else             ip = wkv + 1048576 + (size_t)(z - 20) * 262144;
    op = wall + (size_t)z * 262144;
  } else {
    const int rem = id - 14336;
    c0 = (rem & 63) * 32;
    r0 = (rem >> 6) * 32;
    C = 2048;
    ip = wvec;
    op = wvecT;
  }
  const int tx = threadIdx.x & 31, ty = threadIdx.x >> 5;
#pragma unroll
  for (int k = 0; k < 4; k++)
    tile[ty + k * 8][tx] = ip[(size_t)(r0 + ty + k * 8) * C + c0 + tx];
  __syncthreads();
#pragma unroll
  for (int k = 0; k < 4; k++)
    op[(size_t)(c0 + ty + k * 8) * 2048 + r0 + tx] = f2bf(tile[tx][ty + k * 8]);
}

// ---- vectorized bf16 transpose for V: [bz][2048][128] -> [bz][128][2048] ----
// 64x64 tiles; short4 loads + stores; LDS stride 66 shorts (33 banks, conflict-free).
__global__ void k_trv(const short* __restrict__ in, short* __restrict__ out) {
  __shared__ short t[64][66];
  const int bz = blockIdx.z;
  const int s0 = blockIdx.y * 64, h0 = blockIdx.x * 64;
  const int i = threadIdx.x;
  const int row = i >> 2, q = i & 3;
  const short* ip = in + (size_t)bz * 262144;
  short* op = out + (size_t)bz * 262144;
#pragma unroll
  for (int j = 0; j < 4; j++) {
    const int c = q * 16 + j * 4;
    const short4 v = *reinterpret_cast<const short4*>(ip + (size_t)(s0 + row) * 128 + h0 + c);
    t[row][c] = v.x; t[row][c + 1] = v.y; t[row][c + 2] = v.z; t[row][c + 3] = v.w;
  }
  __syncthreads();
#pragma unroll
  for (int j = 0; j < 4; j++) {
    const int c = q * 16 + j * 4;  // s-offset within tile
    short4 v;
    v.x = t[c][row]; v.y = t[c + 1][row]; v.z = t[c + 2][row]; v.w = t[c + 3][row];
    *reinterpret_cast<short4*>(op + (size_t)(h0 + row) * 2048 + s0 + c) = v;
  }
}

// =================== BMxBNxK 4-phase MFMA GEMM (T2+T3+T4+T5+T1) ===================
// NOTE (r9-r13): frame-bound at ~845 TF; sched-pragma removal, ds_read cuts,
// barrier halving, m201 port, and 2-blocks/CU all measured null. Workhorse.

#define GBAR __builtin_amdgcn_s_barrier()
#define LGK asm volatile("s_waitcnt lgkmcnt(0)")
#define PR1 __builtin_amdgcn_s_setprio(1)
#define PR0 __builtin_amdgcn_s_setprio(0)
#define VMW { if constexpr (LPA + LPB == 4) asm volatile("s_waitcnt vmcnt(4)");       \
              else if constexpr (LPA + LPB == 3) asm volatile("s_waitcnt vmcnt(3)");  \
              else asm volatile("s_waitcnt vmcnt(2)"); }

template <int LN>
DEVINL void stage(char* dst, const short* src, int K, int tid) {
#pragma unroll
  for (int L = 0; L < LN; L++) {
    const int loc = L * 8192 + tid * 16;
    const int row = loc >> 7;
    const int gsw = ((loc >> 4) & 7) ^ (row & 7);
    __builtin_amdgcn_global_load_lds(
        (const __attribute__((address_space(1))) void*)(src + (size_t)row * K + gsw * 8),
        (__attribute__((address_space(3))) void*)(dst + loc), 16, 0, 0);
  }
}

#define SA(BUF, HALF, KT) \
  stage<LPA>((BUF) + (HALF) * (ABY / 2), Am + (size_t)((HALF) * (BM / 2)) * K + (KT) * 64, K, tid)
#define SB(BUF, HALF, KT) \
  stage<LPB>((BUF) + (HALF) * (BBY / 2), Bn + (size_t)((HALF) * (BN / 2)) * K + (KT) * 64, K, tid)

#define RDA(BUF, IH)                                                                   \
  { _Pragma("unroll")                                                                  \
    for (int kf_ = 0; kf_ < KFN; kf_++) {                                              \
      _Pragma("unroll")                                                                \
      for (int kk_ = 0; kk_ < 2; kk_++) {                                              \
        const int row_ = ((IH) * KFN + kf_) * 32 + wr * 16 + lr;                       \
        a[kf_ * 2 + kk_] = *(const bf16x8*)((BUF) + row_ * 128 +                       \
                                            (((kk_ * 4 + lu) ^ (lr & 7)) << 4));       \
      } } }

#define RDB(BUF, JH, ARR)                                                              \
  { _Pragma("unroll")                                                                  \
    for (int jf_ = 0; jf_ < JFN; jf_++) {                                              \
      _Pragma("unroll")                                                                \
      for (int kk_ = 0; kk_ < 2; kk_++) {                                              \
        const int row_ = ((JH) * JFN + jf_) * 64 + wc * 16 + lr;                       \
        ARR[jf_ * 2 + kk_] = *(const bf16x8*)((BUF) + row_ * 128 +                     \
                                              (((kk_ * 4 + lu) ^ (lr & 7)) << 4));     \
      } } }

#define MF(IH, JH, ARR)                                                                \
  { _Pragma("unroll")                                                                  \
    for (int kf_ = 0; kf_ < KFN; kf_++)                                                \
      { _Pragma("unroll")                                                              \
        for (int jf_ = 0; jf_ < JFN; jf_++)                                            \
          { _Pragma("unroll")                                                          \
            for (int kk_ = 0; kk_ < 2; kk_++)                                          \
              acc[(IH) * KFN + kf_][(JH) * JFN + jf_] =                                \
                  __builtin_amdgcn_mfma_f32_16x16x32_bf16(                             \
                      a[kf_ * 2 + kk_], ARR[jf_ * 2 + kk_],                            \
                      acc[(IH) * KFN + kf_][(JH) * JFN + jf_], 0, 0, 0);               \
          } } }

template <int BM, int BN>
__global__ __launch_bounds__(512, 2) void k_gemm256(
    const short* __restrict__ A, const short* __restrict__ Bt,
    void* __restrict__ Out0, void* __restrict__ Out1,
    int N, int K, int mode) {
  constexpr int LPA = BM / 128;
  constexpr int LPB = BN / 128;
  constexpr int KFN = BM / 64;
  constexpr int JFN = BN / 128;
  constexpr int ABY = BM * 128;
  constexpr int BBY = BN * 128;
  extern __shared__ __align__(16) char sm[];
  char* A0 = sm;
  char* A1 = sm + ABY;
  char* B0 = sm + 2 * ABY;
  char* B1 = sm + 2 * ABY + BBY;
  const int lin = blockIdx.x + gridDim.x * blockIdx.y;
  const int nc = N / BN;
  const int m0 = (lin / nc) * BM, n0 = (lin % nc) * BN;
  const int tid = threadIdx.x, lane = tid & 63, w = tid >> 6;
  const int wr = w & 1, wc = w >> 1;
  const int lr = lane & 15, lu = lane >> 4;
  const short* Am = A + (size_t)m0 * K;
  const short* Bn = Bt + (size_t)n0 * K;
  f32x4 acc[KFN * 2][JFN * 2] = {};
  bf16x8 a[KFN * 2], bJ0[JFN * 2], bJ1[JFN * 2];
  const int NIT = K >> 7;
  const int TMAX = (K >> 6) - 1;

  SA(A0, 0, 0); SB(B0, 1, 0); SA(A0, 1, 0); SB(B0, 0, 0);
  SA(A1, 0, 1); SB(B1, 1, 1);
  VMW; GBAR;

  for (int it = 0; it < NIT; ++it) {
    const int t1 = 2 * it + 1;
    const int t2 = (2 * it + 2 < TMAX) ? 2 * it + 2 : TMAX;
    const int t3 = (2 * it + 3 < TMAX) ? 2 * it + 3 : TMAX;
    RDA(A0, 0); RDB(B0, 0, bJ0); RDB(B0, 1, bJ1); SA(A1, 1, t1); SB(B1, 0, t1);
    GBAR; LGK; PR1; MF(0, 0, bJ0); MF(0, 1, bJ1); PR0; GBAR;
    RDA(A0, 1); SA(A0, 0, t2); SB(B0, 1, t2);
    GBAR; LGK; PR1; MF(1, 1, bJ1); MF(1, 0, bJ0); PR0; VMW; GBAR;
    RDA(A1, 0); RDB(B1, 0, bJ0); RDB(B1, 1, bJ1); SA(A0, 1, t2); SB(B0, 0, t2);
    GBAR; LGK; PR1; MF(0, 0, bJ0); MF(0, 1, bJ1); PR0; GBAR;
    RDA(A1, 1); SA(A1, 0, t3); SB(B1, 1, t3);
    GBAR; LGK; PR1; MF(1, 1, bJ1); MF(1, 0, bJ0); PR0; VMW; GBAR;
  }

  if (mode == 2) {
#pragma unroll
    for (int k = 0; k < KFN * 2; k++)
#pragma unroll
      for (int j = 0; j < JFN * 2; j++)
#pragma unroll
        for (int r = 0; r < 4; r++) {
          const int m = m0 + k * 32 + wr * 16 + lu * 4 + r;
          const int n = n0 + j * 64 + wc * 16 + lr;
          ((float*)Out0)[(size_t)m * N + n] = acc[k][j][r];
        }
  } else {
    const int i_rope = wc * 16 + lr;
    const float inv = __expf(-(float)i_rope * (float)(9.210340371976184 / 64.0));
#pragma unroll
    for (int k = 0; k < KFN * 2; k++) {
      float sn[4], cs[4];
#pragma unroll
      for (int r = 0; r < 4; r++) {
        const int m = m0 + k * 32 + wr * 16 + lu * 4 + r;
        sincosf((float)(m & 2047) * inv, &sn[r], &cs[r]);
      }
#pragma unroll
      for (int u = 0; u < JFN; u++) {
        const int n_lo = n0 + (2 * u) * 64 + wc * 16 + lr;
        const int reg = (n_lo < 2048) ? 0 : ((n_lo < 2560) ? 1 : 2);
#pragma unroll
        for (int r = 0; r < 4; r++) {
          const int m = m0 + k * 32 + wr * 16 + lu * 4 + r;
          const int bb = m >> 11, t = m & 2047;
          float lo = acc[k][2 * u][r], hi = acc[k][2 * u + 1][r];
          if (reg < 2) {
            const float l2 = lo * cs[r] - hi * sn[r];
            const float h2 = hi * cs[r] + lo * sn[r];
            const float sc = (reg == 0) ? 0.08838834764831845f : 1.0f;
            lo = l2 * sc; hi = h2 * sc;
          }
#pragma unroll
          for (int p = 0; p < 2; p++) {
            const int n = n_lo + p * 64;
            const float v = p ? hi : lo;
            if (n < 2048) {
              ((short*)Out0)[(((size_t)(bb * 16 + (n >> 7))) << 18) + t * 128 + (n & 127)] =
                  f2bf(v);
            } else {
              const int nn = n - 2048;
              ((short*)Out1)[(((size_t)(((nn >> 9) * 2 + bb) * 4 + ((nn >> 7) & 3))) << 18) +
                             t * 128 + (nn & 127)] = f2bf(v);
            }
          }
        }
      }
    }
  }
}

// ---------------- flash attention, sliding window + tanh soft-cap ----------------
// QBLK=128: 512 threads, 8 waves x 16 t-rows; each K/V tile staged once per 128
// Q-rows (halves staging + barrier count vs QBLK=64). Per-wave math unchanged.
// Swapped QK^T: sc[cg][r] = S[s=s0+cg*16+lu*4+r][t=tw+lr]; cubic soft-cap;
// fixed-max softmax (cap bounds logits); scalar lsum per lane.
__global__ __launch_bounds__(512) void k_attn(
    const short* __restrict__ q, const short* __restrict__ kk,
    const short* __restrict__ vT, short* __restrict__ enc) {
  __shared__ __align__(16) short lK[64 * 128];   // [s][h], byte ^= ((s&7)<<4)
  __shared__ __align__(16) short lV[128 * 64];   // [h][s], byte ^= ((h&7)<<4)
  __shared__ __align__(16) short lP[8][16 * 64]; // per-wave P [t][s], byte ^= ((t&7)<<4)
  const int bn = blockIdx.x, b = bn >> 4, n = bn & 15, kv = n >> 2;
  const int qt0 = (15 - blockIdx.y) * 128;  // heavy blocks dispatched first
  const int tid = threadIdx.x, lane = tid & 63, w = tid >> 6;
  const int lr = lane & 15, lu = lane >> 4;
  const short* qbase = q + (((size_t)(b * 16 + n)) << 18) + (size_t)(qt0 + w * 16) * 128;
  bf16x8 qa[4];
#pragma unroll
  for (int c = 0; c < 4; c++)
    qa[c] = *reinterpret_cast<const bf16x8*>(qbase + lr * 128 + c * 32 + lu * 8);
  f32x4 o[8] = {};
  float lsum = 0.f;
  const short* kbase = kk + (((size_t)(b * 4 + kv)) << 18);
  const short* vbase = vT + (((size_t)(b * 4 + kv)) << 18);
  char* lPw = (char*)lP[w];
  const int tw = qt0 + w * 16;
  const int t_row = tw + lu * 4;
  int st0 = qt0 - 1023; if (st0 < 0) st0 = 0;
  st0 >>= 6;
  const int stE = (qt0 + 127) >> 6;
  for (int st = st0; st <= stE; st++) {
    const int s0 = st << 6;
#pragma unroll
    for (int c = 0; c < 2; c++) {
      const int L = c * 8192 + tid * 16;  // byte offset in 16 KiB tile
      {  // K tile: linear LDS dest, pre-swizzled global source
        const int s = L >> 8, slot = (L >> 4) & 15;
        const int sp = slot ^ (s & 7);
        __builtin_amdgcn_global_load_lds(
            (const __attribute__((address_space(1))) void*)(kbase + (size_t)(s0 + s) * 128 + sp * 8),
            (__attribute__((address_space(3))) void*)((char*)lK + L), 16, 0, 0);
      }
      {  // V tile
        const int h = L >> 7, slot = (L >> 4) & 7;
        const int u = slot ^ (h & 7);
        __builtin_amdgcn_global_load_lds(
            (const __attribute__((address_space(1))) void*)(vbase + (size_t)h * 2048 + s0 + u * 8),
            (__attribute__((address_space(3))) void*)((char*)lV + L), 16, 0, 0);
      }
    }
    __syncthreads();
    // ---- QK^T (swapped) ----
    f32x4 sc[4];
    __builtin_amdgcn_s_setprio(1);
#pragma unroll
    for (int cg = 0; cg < 4; cg++) {
      sc[cg] = (f32x4){0.f, 0.f, 0.f, 0.f};
      const int s = cg * 16 + lr;
      const int sw = (s & 7) << 4;
#pragma unroll
      for (int c = 0; c < 4; c++) {
        bf16x8 kb = *reinterpret_cast<const bf16x8*>((char*)lK + s * 256 + (((c * 4 + lu) << 4) ^ sw));
        sc[cg] = __builtin_amdgcn_mfma_f32_16x16x32_bf16(kb, qa[c], sc[cg], 0, 0, 0);
      }
    }
    __builtin_amdgcn_s_setprio(0);
    // ---- cubic soft-cap + exp, pack pairs, write P (b32) ----
    const bool allv = (s0 + 63 <= tw) && (s0 + 1008 >= tw);
    if (allv) {
#pragma unroll
      for (int cg = 0; cg < 4; cg++) {
        float pr[4];
#pragma unroll
        for (int r = 0; r < 4; r++) {
          const float x = sc[cg][r];
          const float cap = __builtin_fmaf(x * x * x, -1.3333333e-4f, x);
          const float p = __expf(cap);
          lsum += p;
          pr[r] = p;
        }
        unsigned w0, w1;
        asm("v_cvt_pk_bf16_f32 %0, %1, %2" : "=v"(w0) : "v"(pr[0]), "v"(pr[1]));
        asm("v_cvt_pk_bf16_f32 %0, %1, %2" : "=v"(w1) : "v"(pr[2]), "v"(pr[3]));
        const int sb = (cg * 16 + lu * 4) << 1;
        *(unsigned*)(lPw + (lr << 7) + (sb ^ ((lr & 7) << 4))) = w0;
        *(unsigned*)(lPw + (lr << 7) + ((sb + 4) ^ ((lr & 7) << 4))) = w1;
      }
    } else {
      const int t = tw + lr;
#pragma unroll
      for (int cg = 0; cg < 4; cg++) {
        float pr[4];
#pragma unroll
        for (int r = 0; r < 4; r++) {
          const int s = s0 + cg * 16 + lu * 4 + r;
          const bool valid = (s <= t) & (s + 1024 > t);
          const float x = sc[cg][r];
          const float cap = __builtin_fmaf(x * x * x, -1.3333333e-4f, x);
          float p = __expf(cap);
          p = valid ? p : 0.f;
          lsum += p;
          pr[r] = p;
        }
        unsigned w0, w1;
        asm("v_cvt_pk_bf16_f32 %0, %1, %2" : "=v"(w0) : "v"(pr[0]), "v"(pr[1]));
        asm("v_cvt_pk_bf16_f32 %0, %1, %2" : "=v"(w1) : "v"(pr[2]), "v"(pr[3]));
        const int sb = (cg * 16 + lu * 4) << 1;
        *(unsigned*)(lPw + (lr << 7) + (sb ^ ((lr & 7) << 4))) = w0;
        *(unsigned*)(lPw + (lr << 7) + ((sb + 4) ^ ((lr & 7) << 4))) = w1;
      }
    }
    // ---- PV ----
#pragma unroll
    for (int ks = 0; ks < 2; ks++) {
      const bf16x8 pf = *reinterpret_cast<const bf16x8*>(
          lPw + (lr << 7) + ((ks * 64 + lu * 16) ^ ((lr & 7) << 4)));
      __builtin_amdgcn_s_setprio(1);
#pragma unroll
      for (int oc = 0; oc < 8; oc++) {
        const int h = oc * 16 + lr;
        bf16x8 vb = *reinterpret_cast<const bf16x8*>(
            (char*)lV + h * 128 + (((ks * 4 + lu) << 4) ^ ((h & 7) << 4)));
        o[oc] = __builtin_amdgcn_mfma_f32_16x16x32_bf16(pf, vb, o[oc], 0, 0, 0);
      }
      __builtin_amdgcn_s_setprio(0);
    }
    __syncthreads();
  }
  // ---- reduce: lane holds partial sum for column t=tw+lr ----
  float tot = lsum;
  tot += __shfl_xor(tot, 16, 64);
  tot += __shfl_xor(tot, 32, 64);
  float rs[4];
#pragma unroll
  for (int r = 0; r < 4; r++)
    rs[r] = 1.f / __shfl(tot, lu * 4 + r, 64);
#pragma unroll
  for (int oc = 0; oc < 8; oc++)
#pragma unroll
    for (int r = 0; r < 4; r++) {
      const int t = t_row + r;
      enc[((size_t)b * 2048 + t) * 2048 + n * 128 + oc * 16 + lr] = f2bf(o[oc][r] * rs[r]);
    }
}

extern "C" void kernel_launch(void* const* d_in, const int* in_sizes, int n_in,
                              void* d_out, int out_size, void* d_ws, size_t ws_size,
                              hipStream_t stream) {
  (void)in_sizes; (void)n_in; (void)out_size; (void)ws_size;
  const float* x    = (const float*)d_in[0];
  const float* wq   = (const float*)d_in[3];
  const float* wkv  = (const float*)d_in[4];
  const float* wvec = (const float*)d_in[5];
  char* ws = (char*)d_ws;
  size_t off = 0;
  short* xbf   = (short*)(ws + off); off += (size_t)8388608 * 2;            // x bf16 [B*T][D]
  short* wall  = (short*)(ws + off); off += (size_t)3072 * 2048 * 2;        // [wqT|wkT|wvT] rows x K
  short* wvecT = (short*)(ws + off); off += (size_t)2048 * 2048 * 2;        // [d][nh]
  short* qbuf  = (short*)(ws + off); off += (size_t)2 * 16 * 2048 * 128 * 2; // q bf16 [b][n][t][h]
  short* kvbuf = (short*)(ws + off); off += (size_t)2 * 2 * 4 * 2048 * 128 * 2; // [c][b][kv][t][h]
  short* vTbuf = (short*)(ws + off); off += (size_t)2 * 4 * 128 * 2048 * 2; // v^T [b][kv][h][s]
  short* encb  = (short*)(ws + off); off += (size_t)2 * 2048 * 2048 * 2;    // [b][t][nh]

  hipFuncSetAttribute(reinterpret_cast<const void*>(&k_gemm256<128, 384>),
                      hipFuncAttributeMaxDynamicSharedMemorySize, 131072);
  hipFuncSetAttribute(reinterpret_cast<const void*>(&k_gemm256<128, 256>),
                      hipFuncAttributeMaxDynamicSharedMemorySize, 98304);

  k_prep<<<18432, 256, 0, stream>>>(x, wq, wkv, wvec, xbf, wall, wvecT);
  k_gemm256<128, 384><<<dim3(32, 8), 512, 131072, stream>>>(xbf, wall, qbuf, kvbuf,
                                                            3072, 2048, 0);
  k_trv<<<dim3(2, 32, 8), 256, 0, stream>>>(kvbuf + 2097152, vTbuf);
  k_attn<<<dim3(32, 16), 512, 0, stream>>>(qbuf, kvbuf, vTbuf, encb);
  k_gemm256<128, 256><<<dim3(32, 8), 512, 98304, stream>>>(encb, wvecT, d_out, nullptr,
                                                           2048, 2048, 2);
}

// Round 17
// 161.556 us; speedup vs baseline: 1.3096x; 1.0199x over previous
//
#include <hip/hip_runtime.h>
#include <hip/hip_bf16.h>

#define DEVINL static __device__ __forceinline__

typedef __attribute__((ext_vector_type(4))) float f32x4;
typedef __attribute__((ext_vector_type(8))) short bf16x8;

DEVINL short f2bf(float f) {
  __hip_bfloat16 h = __float2bfloat16(f);
  union { __hip_bfloat16 h; short s; } u; u.h = h; return u.s;
}
DEVINL float bf2f(short s) {
  union { unsigned u; float f; } v; v.u = ((unsigned)(unsigned short)s) << 16;
  return v.f;
}

// ---- prep: x f32->bf16 convert + ALL weight transposes in ONE launch ----
// id < 8192: cvt path (4 f32->bf16 per thread from x).
// 8192 <= id < 14336: 24 batches of [2048][128] -> wall (wq 0-15, wk 16-19, wv 20-23).
// id >= 14336: wvec [2048][2048] -> wvecT, 64x64 blocks of 32x32 tiles.
__global__ void k_prep(const float* __restrict__ x, const float* __restrict__ wq,
                       const float* __restrict__ wkv, const float* __restrict__ wvec,
                       short* __restrict__ xbf, short* __restrict__ wall,
                       short* __restrict__ wvecT) {
  __shared__ float tile[32][33];
  const int id = blockIdx.x;
  if (id < 8192) {
    const int i = id * 256 + threadIdx.x;
    const float4 v = reinterpret_cast<const float4*>(x)[i];
    short4 o;
    o.x = f2bf(v.x); o.y = f2bf(v.y); o.z = f2bf(v.z); o.w = f2bf(v.w);
    reinterpret_cast<short4*>(xbf)[i] = o;
    return;
  }
  const float* ip;
  short* op;
  int C, r0, c0;
  if (id < 14336) {
    const int zid = id - 8192;
    const int z = zid >> 8, rem = zid & 255;
    c0 = (rem & 3) * 32;
    r0 = (rem >> 2) * 32;
    C = 128;
    if (z < 16)      ip = wq + (size_t)z * 262144;
    else if (z < 20) ip = wkv + (size_t)(z - 16) * 262144;
    else             ip = wkv + 1048576 + (size_t)(z - 20) * 262144;
    op = wall + (size_t)z * 262144;
  } else {
    const int rem = id - 14336;
    c0 = (rem & 63) * 32;
    r0 = (rem >> 6) * 32;
    C = 2048;
    ip = wvec;
    op = wvecT;
  }
  const int tx = threadIdx.x & 31, ty = threadIdx.x >> 5;
#pragma unroll
  for (int k = 0; k < 4; k++)
    tile[ty + k * 8][tx] = ip[(size_t)(r0 + ty + k * 8) * C + c0 + tx];
  __syncthreads();
#pragma unroll
  for (int k = 0; k < 4; k++)
    op[(size_t)(c0 + ty + k * 8) * 2048 + r0 + tx] = f2bf(tile[tx][ty + k * 8]);
}

// =================== BMxBNxK 4-phase MFMA GEMM (T2+T3+T4+T5+T1) ===================
// NOTE (r9-r13): frame-bound at ~845 TF; sched-pragma removal, ds_read cuts,
// barrier halving, m201 port, and 2-blocks/CU all measured null. Workhorse.
// mode 0 epilogue: q/k fused-RoPE scatter; V written TRANSPOSED (short4 runs of
// 4 consecutive s) directly to vT — removes the separate transpose kernel.

#define GBAR __builtin_amdgcn_s_barrier()
#define LGK asm volatile("s_waitcnt lgkmcnt(0)")
#define PR1 __builtin_amdgcn_s_setprio(1)
#define PR0 __builtin_amdgcn_s_setprio(0)
#define VMW { if constexpr (LPA + LPB == 4) asm volatile("s_waitcnt vmcnt(4)");       \
              else if constexpr (LPA + LPB == 3) asm volatile("s_waitcnt vmcnt(3)");  \
              else asm volatile("s_waitcnt vmcnt(2)"); }

template <int LN>
DEVINL void stage(char* dst, const short* src, int K, int tid) {
#pragma unroll
  for (int L = 0; L < LN; L++) {
    const int loc = L * 8192 + tid * 16;
    const int row = loc >> 7;
    const int gsw = ((loc >> 4) & 7) ^ (row & 7);
    __builtin_amdgcn_global_load_lds(
        (const __attribute__((address_space(1))) void*)(src + (size_t)row * K + gsw * 8),
        (__attribute__((address_space(3))) void*)(dst + loc), 16, 0, 0);
  }
}

#define SA(BUF, HALF, KT) \
  stage<LPA>((BUF) + (HALF) * (ABY / 2), Am + (size_t)((HALF) * (BM / 2)) * K + (KT) * 64, K, tid)
#define SB(BUF, HALF, KT) \
  stage<LPB>((BUF) + (HALF) * (BBY / 2), Bn + (size_t)((HALF) * (BN / 2)) * K + (KT) * 64, K, tid)

#define RDA(BUF, IH)                                                                   \
  { _Pragma("unroll")                                                                  \
    for (int kf_ = 0; kf_ < KFN; kf_++) {                                              \
      _Pragma("unroll")                                                                \
      for (int kk_ = 0; kk_ < 2; kk_++) {                                              \
        const int row_ = ((IH) * KFN + kf_) * 32 + wr * 16 + lr;                       \
        a[kf_ * 2 + kk_] = *(const bf16x8*)((BUF) + row_ * 128 +                       \
                                            (((kk_ * 4 + lu) ^ (lr & 7)) << 4));       \
      } } }

#define RDB(BUF, JH, ARR)                                                              \
  { _Pragma("unroll")                                                                  \
    for (int jf_ = 0; jf_ < JFN; jf_++) {                                              \
      _Pragma("unroll")                                                                \
      for (int kk_ = 0; kk_ < 2; kk_++) {                                              \
        const int row_ = ((JH) * JFN + jf_) * 64 + wc * 16 + lr;                       \
        ARR[jf_ * 2 + kk_] = *(const bf16x8*)((BUF) + row_ * 128 +                     \
                                              (((kk_ * 4 + lu) ^ (lr & 7)) << 4));     \
      } } }

#define MF(IH, JH, ARR)                                                                \
  { _Pragma("unroll")                                                                  \
    for (int kf_ = 0; kf_ < KFN; kf_++)                                                \
      { _Pragma("unroll")                                                              \
        for (int jf_ = 0; jf_ < JFN; jf_++)                                            \
          { _Pragma("unroll")                                                          \
            for (int kk_ = 0; kk_ < 2; kk_++)                                          \
              acc[(IH) * KFN + kf_][(JH) * JFN + jf_] =                                \
                  __builtin_amdgcn_mfma_f32_16x16x32_bf16(                             \
                      a[kf_ * 2 + kk_], ARR[jf_ * 2 + kk_],                            \
                      acc[(IH) * KFN + kf_][(JH) * JFN + jf_], 0, 0, 0);               \
          } } }

template <int BM, int BN>
__global__ __launch_bounds__(512, 2) void k_gemm256(
    const short* __restrict__ A, const short* __restrict__ Bt,
    void* __restrict__ Out0, void* __restrict__ Out1, void* __restrict__ Out2,
    int N, int K, int mode) {
  constexpr int LPA = BM / 128;
  constexpr int LPB = BN / 128;
  constexpr int KFN = BM / 64;
  constexpr int JFN = BN / 128;
  constexpr int ABY = BM * 128;
  constexpr int BBY = BN * 128;
  extern __shared__ __align__(16) char sm[];
  char* A0 = sm;
  char* A1 = sm + ABY;
  char* B0 = sm + 2 * ABY;
  char* B1 = sm + 2 * ABY + BBY;
  const int lin = blockIdx.x + gridDim.x * blockIdx.y;
  const int nc = N / BN;
  const int m0 = (lin / nc) * BM, n0 = (lin % nc) * BN;
  const int tid = threadIdx.x, lane = tid & 63, w = tid >> 6;
  const int wr = w & 1, wc = w >> 1;
  const int lr = lane & 15, lu = lane >> 4;
  const short* Am = A + (size_t)m0 * K;
  const short* Bn = Bt + (size_t)n0 * K;
  f32x4 acc[KFN * 2][JFN * 2] = {};
  bf16x8 a[KFN * 2], bJ0[JFN * 2], bJ1[JFN * 2];
  const int NIT = K >> 7;
  const int TMAX = (K >> 6) - 1;

  SA(A0, 0, 0); SB(B0, 1, 0); SA(A0, 1, 0); SB(B0, 0, 0);
  SA(A1, 0, 1); SB(B1, 1, 1);
  VMW; GBAR;

  for (int it = 0; it < NIT; ++it) {
    const int t1 = 2 * it + 1;
    const int t2 = (2 * it + 2 < TMAX) ? 2 * it + 2 : TMAX;
    const int t3 = (2 * it + 3 < TMAX) ? 2 * it + 3 : TMAX;
    RDA(A0, 0); RDB(B0, 0, bJ0); RDB(B0, 1, bJ1); SA(A1, 1, t1); SB(B1, 0, t1);
    GBAR; LGK; PR1; MF(0, 0, bJ0); MF(0, 1, bJ1); PR0; GBAR;
    RDA(A0, 1); SA(A0, 0, t2); SB(B0, 1, t2);
    GBAR; LGK; PR1; MF(1, 1, bJ1); MF(1, 0, bJ0); PR0; VMW; GBAR;
    RDA(A1, 0); RDB(B1, 0, bJ0); RDB(B1, 1, bJ1); SA(A0, 1, t2); SB(B0, 0, t2);
    GBAR; LGK; PR1; MF(0, 0, bJ0); MF(0, 1, bJ1); PR0; GBAR;
    RDA(A1, 1); SA(A1, 0, t3); SB(B1, 1, t3);
    GBAR; LGK; PR1; MF(1, 1, bJ1); MF(1, 0, bJ0); PR0; VMW; GBAR;
  }

  if (mode == 2) {
#pragma unroll
    for (int k = 0; k < KFN * 2; k++)
#pragma unroll
      for (int j = 0; j < JFN * 2; j++)
#pragma unroll
        for (int r = 0; r < 4; r++) {
          const int m = m0 + k * 32 + wr * 16 + lu * 4 + r;
          const int n = n0 + j * 64 + wc * 16 + lr;
          ((float*)Out0)[(size_t)m * N + n] = acc[k][j][r];
        }
  } else {
    const int i_rope = wc * 16 + lr;
    const float inv = __expf(-(float)i_rope * (float)(9.210340371976184 / 64.0));
    const bool has_qk = (n0 < 2560);  // uniform: block contains q or k columns
#pragma unroll
    for (int k = 0; k < KFN * 2; k++) {
      const int m_base = m0 + k * 32 + wr * 16 + lu * 4;
      const int bb = m_base >> 11, t0 = m_base & 2047;
      float sn[4], cs[4];
      if (has_qk) {
#pragma unroll
        for (int r = 0; r < 4; r++)
          sincosf((float)(t0 + r) * inv, &sn[r], &cs[r]);
      }
#pragma unroll
      for (int u = 0; u < JFN; u++) {
        const int n_lo = n0 + (2 * u) * 64 + wc * 16 + lr;
        const int reg = (n_lo < 2048) ? 0 : ((n_lo < 2560) ? 1 : 2);  // q/k/v
        if (reg == 2) {
          // V: write transposed directly to vT [b][kv][h][s]; r spans 4 consecutive s.
#pragma unroll
          for (int p = 0; p < 2; p++) {
            const int nn = n_lo + p * 64 - 2560;
            short4 v4;
            v4.x = f2bf(acc[k][2 * u + p][0]);
            v4.y = f2bf(acc[k][2 * u + p][1]);
            v4.z = f2bf(acc[k][2 * u + p][2]);
            v4.w = f2bf(acc[k][2 * u + p][3]);
            *reinterpret_cast<short4*>((short*)Out2 + (((size_t)(bb * 4 + (nn >> 7))) << 18) +
                                       (size_t)(nn & 127) * 2048 + t0) = v4;
          }
        } else {
#pragma unroll
          for (int r = 0; r < 4; r++) {
            const int t = t0 + r;
            float lo = acc[k][2 * u][r], hi = acc[k][2 * u + 1][r];
            const float l2 = lo * cs[r] - hi * sn[r];
            const float h2 = hi * cs[r] + lo * sn[r];
            const float sc = (reg == 0) ? 0.08838834764831845f : 1.0f;
            lo = l2 * sc; hi = h2 * sc;
#pragma unroll
            for (int p = 0; p < 2; p++) {
              const int n = n_lo + p * 64;
              const float v = p ? hi : lo;
              if (n < 2048) {  // q: [b][head][t][h]
                ((short*)Out0)[(((size_t)(bb * 16 + (n >> 7))) << 18) + t * 128 + (n & 127)] =
                    f2bf(v);
              } else {  // k: [b][kv][t][h]
                const int nn = n - 2048;
                ((short*)Out1)[(((size_t)(bb * 4 + (nn >> 7))) << 18) + t * 128 + (nn & 127)] =
                    f2bf(v);
              }
            }
          }
        }
      }
    }
  }
}

// ---------------- flash attention, sliding window + tanh soft-cap ----------------
// QBLK=128: 512 threads, 8 waves x 16 t-rows; each K/V tile staged once per 128
// Q-rows. Swapped QK^T; cubic soft-cap; fixed-max softmax; scalar lsum per lane.
__global__ __launch_bounds__(512) void k_attn(
    const short* __restrict__ q, const short* __restrict__ kk,
    const short* __restrict__ vT, short* __restrict__ enc) {
  __shared__ __align__(16) short lK[64 * 128];   // [s][h], byte ^= ((s&7)<<4)
  __shared__ __align__(16) short lV[128 * 64];   // [h][s], byte ^= ((h&7)<<4)
  __shared__ __align__(16) short lP[8][16 * 64]; // per-wave P [t][s], byte ^= ((t&7)<<4)
  const int bn = blockIdx.x, b = bn >> 4, n = bn & 15, kv = n >> 2;
  const int qt0 = (15 - blockIdx.y) * 128;  // heavy blocks dispatched first
  const int tid = threadIdx.x, lane = tid & 63, w = tid >> 6;
  const int lr = lane & 15, lu = lane >> 4;
  const short* qbase = q + (((size_t)(b * 16 + n)) << 18) + (size_t)(qt0 + w * 16) * 128;
  bf16x8 qa[4];
#pragma unroll
  for (int c = 0; c < 4; c++)
    qa[c] = *reinterpret_cast<const bf16x8*>(qbase + lr * 128 + c * 32 + lu * 8);
  f32x4 o[8] = {};
  float lsum = 0.f;
  const short* kbase = kk + (((size_t)(b * 4 + kv)) << 18);
  const short* vbase = vT + (((size_t)(b * 4 + kv)) << 18);
  char* lPw = (char*)lP[w];
  const int tw = qt0 + w * 16;
  const int t_row = tw + lu * 4;
  int st0 = qt0 - 1023; if (st0 < 0) st0 = 0;
  st0 >>= 6;
  const int stE = (qt0 + 127) >> 6;
  for (int st = st0; st <= stE; st++) {
    const int s0 = st << 6;
#pragma unroll
    for (int c = 0; c < 2; c++) {
      const int L = c * 8192 + tid * 16;
      {  // K tile: linear LDS dest, pre-swizzled global source
        const int s = L >> 8, slot = (L >> 4) & 15;
        const int sp = slot ^ (s & 7);
        __builtin_amdgcn_global_load_lds(
            (const __attribute__((address_space(1))) void*)(kbase + (size_t)(s0 + s) * 128 + sp * 8),
            (__attribute__((address_space(3))) void*)((char*)lK + L), 16, 0, 0);
      }
      {  // V tile
        const int h = L >> 7, slot = (L >> 4) & 7;
        const int u = slot ^ (h & 7);
        __builtin_amdgcn_global_load_lds(
            (const __attribute__((address_space(1))) void*)(vbase + (size_t)h * 2048 + s0 + u * 8),
            (__attribute__((address_space(3))) void*)((char*)lV + L), 16, 0, 0);
      }
    }
    __syncthreads();
    // ---- QK^T (swapped) ----
    f32x4 sc[4];
    __builtin_amdgcn_s_setprio(1);
#pragma unroll
    for (int cg = 0; cg < 4; cg++) {
      sc[cg] = (f32x4){0.f, 0.f, 0.f, 0.f};
      const int s = cg * 16 + lr;
      const int sw = (s & 7) << 4;
#pragma unroll
      for (int c = 0; c < 4; c++) {
        bf16x8 kb = *reinterpret_cast<const bf16x8*>((char*)lK + s * 256 + (((c * 4 + lu) << 4) ^ sw));
        sc[cg] = __builtin_amdgcn_mfma_f32_16x16x32_bf16(kb, qa[c], sc[cg], 0, 0, 0);
      }
    }
    __builtin_amdgcn_s_setprio(0);
    // ---- cubic soft-cap + exp, pack pairs, write P (b32) ----
    const bool allv = (s0 + 63 <= tw) && (s0 + 1008 >= tw);
    if (allv) {
#pragma unroll
      for (int cg = 0; cg < 4; cg++) {
        float pr[4];
#pragma unroll
        for (int r = 0; r < 4; r++) {
          const float x = sc[cg][r];
          const float cap = __builtin_fmaf(x * x * x, -1.3333333e-4f, x);
          const float p = __expf(cap);
          lsum += p;
          pr[r] = p;
        }
        unsigned w0, w1;
        asm("v_cvt_pk_bf16_f32 %0, %1, %2" : "=v"(w0) : "v"(pr[0]), "v"(pr[1]));
        asm("v_cvt_pk_bf16_f32 %0, %1, %2" : "=v"(w1) : "v"(pr[2]), "v"(pr[3]));
        const int sb = (cg * 16 + lu * 4) << 1;
        *(unsigned*)(lPw + (lr << 7) + (sb ^ ((lr & 7) << 4))) = w0;
        *(unsigned*)(lPw + (lr << 7) + ((sb + 4) ^ ((lr & 7) << 4))) = w1;
      }
    } else {
      const int t = tw + lr;
#pragma unroll
      for (int cg = 0; cg < 4; cg++) {
        float pr[4];
#pragma unroll
        for (int r = 0; r < 4; r++) {
          const int s = s0 + cg * 16 + lu * 4 + r;
          const bool valid = (s <= t) & (s + 1024 > t);
          const float x = sc[cg][r];
          const float cap = __builtin_fmaf(x * x * x, -1.3333333e-4f, x);
          float p = __expf(cap);
          p = valid ? p : 0.f;
          lsum += p;
          pr[r] = p;
        }
        unsigned w0, w1;
        asm("v_cvt_pk_bf16_f32 %0, %1, %2" : "=v"(w0) : "v"(pr[0]), "v"(pr[1]));
        asm("v_cvt_pk_bf16_f32 %0, %1, %2" : "=v"(w1) : "v"(pr[2]), "v"(pr[3]));
        const int sb = (cg * 16 + lu * 4) << 1;
        *(unsigned*)(lPw + (lr << 7) + (sb ^ ((lr & 7) << 4))) = w0;
        *(unsigned*)(lPw + (lr << 7) + ((sb + 4) ^ ((lr & 7) << 4))) = w1;
      }
    }
    // ---- PV ----
#pragma unroll
    for (int ks = 0; ks < 2; ks++) {
      const bf16x8 pf = *reinterpret_cast<const bf16x8*>(
          lPw + (lr << 7) + ((ks * 64 + lu * 16) ^ ((lr & 7) << 4)));
      __builtin_amdgcn_s_setprio(1);
#pragma unroll
      for (int oc = 0; oc < 8; oc++) {
        const int h = oc * 16 + lr;
        bf16x8 vb = *reinterpret_cast<const bf16x8*>(
            (char*)lV + h * 128 + (((ks * 4 + lu) << 4) ^ ((h & 7) << 4)));
        o[oc] = __builtin_amdgcn_mfma_f32_16x16x32_bf16(pf, vb, o[oc], 0, 0, 0);
      }
      __builtin_amdgcn_s_setprio(0);
    }
    __syncthreads();
  }
  // ---- reduce: lane holds partial sum for column t=tw+lr ----
  float tot = lsum;
  tot += __shfl_xor(tot, 16, 64);
  tot += __shfl_xor(tot, 32, 64);
  float rs[4];
#pragma unroll
  for (int r = 0; r < 4; r++)
    rs[r] = 1.f / __shfl(tot, lu * 4 + r, 64);
#pragma unroll
  for (int oc = 0; oc < 8; oc++)
#pragma unroll
    for (int r = 0; r < 4; r++) {
      const int t = t_row + r;
      enc[((size_t)b * 2048 + t) * 2048 + n * 128 + oc * 16 + lr] = f2bf(o[oc][r] * rs[r]);
    }
}

extern "C" void kernel_launch(void* const* d_in, const int* in_sizes, int n_in,
                              void* d_out, int out_size, void* d_ws, size_t ws_size,
                              hipStream_t stream) {
  (void)in_sizes; (void)n_in; (void)out_size; (void)ws_size;
  const float* x    = (const float*)d_in[0];
  const float* wq   = (const float*)d_in[3];
  const float* wkv  = (const float*)d_in[4];
  const float* wvec = (const float*)d_in[5];
  char* ws = (char*)d_ws;
  size_t off = 0;
  short* xbf   = (short*)(ws + off); off += (size_t)8388608 * 2;            // x bf16 [B*T][D]
  short* wall  = (short*)(ws + off); off += (size_t)3072 * 2048 * 2;        // [wqT|wkT|wvT] rows x K
  short* wvecT = (short*)(ws + off); off += (size_t)2048 * 2048 * 2;        // [d][nh]
  short* qbuf  = (short*)(ws + off); off += (size_t)2 * 16 * 2048 * 128 * 2; // q bf16 [b][n][t][h]
  short* kbuf  = (short*)(ws + off); off += (size_t)2 * 4 * 2048 * 128 * 2;  // k bf16 [b][kv][t][h]
  short* vTbuf = (short*)(ws + off); off += (size_t)2 * 4 * 128 * 2048 * 2;  // v^T [b][kv][h][s]
  short* encb  = (short*)(ws + off); off += (size_t)2 * 2048 * 2048 * 2;     // [b][t][nh]

  hipFuncSetAttribute(reinterpret_cast<const void*>(&k_gemm256<128, 384>),
                      hipFuncAttributeMaxDynamicSharedMemorySize, 131072);
  hipFuncSetAttribute(reinterpret_cast<const void*>(&k_gemm256<128, 256>),
                      hipFuncAttributeMaxDynamicSharedMemorySize, 98304);

  k_prep<<<18432, 256, 0, stream>>>(x, wq, wkv, wvec, xbf, wall, wvecT);
  k_gemm256<128, 384><<<dim3(32, 8), 512, 131072, stream>>>(xbf, wall, qbuf, kbuf, vTbuf,
                                                            3072, 2048, 0);
  k_attn<<<dim3(32, 16), 512, 0, stream>>>(qbuf, kbuf, vTbuf, encb);
  k_gemm256<128, 256><<<dim3(32, 8), 512, 98304, stream>>>(encb, wvecT, d_out, nullptr, nullptr,
                                                           2048, 2048, 2);
}